// Round 13
// baseline (155.717 us; speedup 1.0000x reference)
//
#include <hip/hip_runtime.h>
#include <stdint.h>

typedef __bf16 bf16x8 __attribute__((ext_vector_type(8)));
typedef float f32x4 __attribute__((ext_vector_type(4)));
typedef float f32x16 __attribute__((ext_vector_type(16)));

#define NEG_BIG2 (-1.442695040e9f)      // -1e9 * log2(e)
#define SC_LOG2  (0.180336880f)         // 0.125 * log2(e)

__device__ __forceinline__ unsigned short f2b(float f) {
  union { float f; unsigned int u; } c; c.f = f;
  unsigned int u = c.u;
  u += 0x7FFFu + ((u >> 16) & 1u);
  return (unsigned short)(u >> 16);
}
__device__ __forceinline__ float b2f(unsigned short h) {
  union { unsigned int u; float f; } c; c.u = ((unsigned int)h) << 16;
  return c.f;
}
__device__ __forceinline__ unsigned int pk2(float a, float b) {
  __bf16 x = (__bf16)a, y = (__bf16)b;
  unsigned short xu, yu;
  __builtin_memcpy(&xu, &x, 2);
  __builtin_memcpy(&yu, &y, 2);
  return (unsigned)xu | ((unsigned)yu << 16);
}
// raw v_exp_f32: D = 2^x
__device__ __forceinline__ float ex2(float x) {
  float r; asm("v_exp_f32 %0, %1" : "=v"(r) : "v"(x)); return r;
}

// global -> LDS direct (16B per lane)
typedef const __attribute__((address_space(1))) unsigned int ga_u32;
typedef __attribute__((address_space(3))) unsigned int ls_u32;
__device__ __forceinline__ void gld16(const void* g, void* l) {
  __builtin_amdgcn_global_load_lds((ga_u32*)g, (ls_u32*)l, 16, 0, 0);
}

__device__ __forceinline__ void swap_pair(unsigned a, unsigned b, int hi,
                                          unsigned& lo_out, unsigned& hi_out) {
#if __has_builtin(__builtin_amdgcn_permlane32_swap)
  auto r = __builtin_amdgcn_permlane32_swap(a, b, false, false);
  lo_out = r[0]; hi_out = r[1];
#else
  unsigned pa = __shfl_xor(a, 32), pb = __shfl_xor(b, 32);
  lo_out = hi ? pb : a;
  hi_out = hi ? b : pa;
#endif
}

// ---------------- RoPE sin/cos table (T x 64) ----------------
__global__ void rope_table_k(float* __restrict__ sin_t, float* __restrict__ cos_t) {
  int i = blockIdx.x * blockDim.x + threadIdx.x;  // 2048*64
  int t = i >> 6, d = i & 63, f = d & 31;
  double inv = exp(-((double)(2 * f) / 64.0) * log(10000.0));
  double ang = (double)t * inv;
  sin_t[i] = (float)sin(ang);
  cos_t[i] = (float)cos(ang);
}

// ---------------- key_padding_mask dtype detector ----------------
__global__ void detect_mask_k(const unsigned int* __restrict__ kpm, int* __restrict__ flag) {
  unsigned int v = 0;
  for (int i = threadIdx.x; i < 1024; i += 256) v |= kpm[i];
  if (v & ~1u) atomicOr(flag, 1);
}

// ---------------- pack key_padding_mask into per-(b, kv64) 64-bit masks -------
__global__ void mask_pack_k(const void* __restrict__ kpm, const int* __restrict__ mflag,
                            unsigned long long* __restrict__ pmask) {
  const int w = threadIdx.x >> 6, lane = threadIdx.x & 63;
  const int bytes = *mflag;
  for (int i = w; i < 64; i += 4) {
    int b = i >> 5, kb = i & 31;
    int idx = b * 2048 + kb * 64 + lane;
    int pad = bytes ? (int)((const unsigned char*)kpm)[idx] : ((const int*)kpm)[idx];
    unsigned long long pm = __ballot(pad != 0);
    if (lane == 0) pmask[i] = pm;
  }
}

// ---------------- convert 4 weight matrices fp32 -> bf16 ----------------------
__global__ void convw_k(const float* __restrict__ Wq, const float* __restrict__ Wk,
                        const float* __restrict__ Wv, const float* __restrict__ Wo,
                        unsigned short* __restrict__ Wb) {
  size_t g = (size_t)blockIdx.x * 256 + threadIdx.x;
  size_t i8 = g * 8;
  int t = (int)(i8 >> 20);
  const float* src = (t == 0 ? Wq : t == 1 ? Wk : t == 2 ? Wv : Wo) + (i8 & 1048575);
  float4 a = *(const float4*)src, c = *(const float4*)(src + 4);
  uint4 o = { pk2(a.x, a.y), pk2(a.z, a.w), pk2(c.x, c.y), pk2(c.z, c.w) };
  *(uint4*)&Wb[i8] = o;
}

// ---------------- convert q,k,v fp32 -> bf16 ------------------
__global__ void conv_in_k(const float* __restrict__ q, const float* __restrict__ k,
                          const float* __restrict__ v, unsigned short* __restrict__ qb,
                          unsigned short* __restrict__ kb, unsigned short* __restrict__ vb) {
  size_t g = (size_t)blockIdx.x * 256 + threadIdx.x;  // 8-elem groups
  size_t i8 = g * 8;
  int t = (int)(i8 >> 22);
  size_t off = i8 & 4194303;
  const float* src = (t == 0 ? q : t == 1 ? k : v) + off;
  unsigned short* dst = (t == 0 ? qb : t == 1 ? kb : vb) + off;
  float4 a = *(const float4*)src, c = *(const float4*)(src + 4);
  uint4 o = { pk2(a.x, a.y), pk2(a.z, a.w), pk2(c.x, c.y), pk2(c.z, c.w) };
  *(uint4*)dst = o;
}

// ---------------- fused QKV projection GEMM (grid.z selects q/k/v) ------------
// z=0 -> qh (b,h,t,d); z=1 -> kh (b,h,t,d); z=2 -> vt (b,h,d,t)
// Double-buffered LDS, ONE barrier per K-step (T3 minimum 2-phase).
template<bool ABF>
__global__ __launch_bounds__(256) void qkv_k(const void* __restrict__ A0,
                                             const void* __restrict__ A1,
                                             const void* __restrict__ A2,
                                             const unsigned short* __restrict__ Wb,
                                             unsigned short* __restrict__ qh,
                                             unsigned short* __restrict__ kh,
                                             unsigned short* __restrict__ vt) {
  const int z = blockIdx.z;
  const void* Ap = (z == 0) ? A0 : (z == 1) ? A1 : A2;
  const unsigned short* Wp = Wb + (size_t)z * 1048576;
  unsigned short* outp = (z == 0) ? qh : (z == 1) ? kh : vt;

  __shared__ unsigned short As[2][128 * 32];
  __shared__ unsigned short Bs[2][128 * 32];
  const int M0 = blockIdx.x * 128, N0 = blockIdx.y * 128;
  const int tid = threadIdx.x, lane = tid & 63, w = tid >> 6;
  const int wr = w >> 1, wc = w & 1;
  const int lrow = lane & 15, lgrp = lane >> 4;

  const f32x4 Z4 = {0.f, 0.f, 0.f, 0.f};
  f32x4 acc[4][4];
#pragma unroll
  for (int i = 0; i < 4; ++i)
#pragma unroll
    for (int j = 0; j < 4; ++j) acc[i][j] = Z4;

  auto STAGE = [&](int bu, int kt) {
    if (ABF) {
      const unsigned short* Ab = (const unsigned short*)Ap;
#pragma unroll
      for (int i = 0; i < 2; ++i) {
        const unsigned short* gA = Ab +
            (size_t)(M0 + i * 64 + w * 16 + (lane >> 2)) * 1024 + kt + (lane & 3) * 8;
        gld16(gA, &As[bu][i * 2048 + w * 512]);
      }
    } else {
      const int row = tid >> 1, half = tid & 1;
      const float* ap = (const float*)Ap + (size_t)(M0 + row) * 1024 + kt + half * 16;
      float4 f0 = *(const float4*)ap, f1 = *(const float4*)(ap + 4);
      float4 f2 = *(const float4*)(ap + 8), f3 = *(const float4*)(ap + 12);
      uint4 u0 = { pk2(f0.x, f0.y), pk2(f0.z, f0.w), pk2(f1.x, f1.y), pk2(f1.z, f1.w) };
      uint4 u1 = { pk2(f2.x, f2.y), pk2(f2.z, f2.w), pk2(f3.x, f3.y), pk2(f3.z, f3.w) };
      *(uint4*)&As[bu][row * 32 + half * 16] = u0;
      *(uint4*)&As[bu][row * 32 + half * 16 + 8] = u1;
    }
#pragma unroll
    for (int i = 0; i < 2; ++i) {
      const unsigned short* gB = Wp +
          (size_t)(N0 + i * 64 + w * 16 + (lane >> 2)) * 1024 + kt + (lane & 3) * 8;
      gld16(gB, &Bs[bu][i * 2048 + w * 512]);
    }
  };

  STAGE(0, 0);
  int cur = 0;
  for (int kt = 0; kt < 1024; kt += 32) {
    __syncthreads();
    if (kt + 32 < 1024) STAGE(cur ^ 1, kt + 32);
    bf16x8 af[4], bfv[4];
#pragma unroll
    for (int m = 0; m < 4; ++m)
      af[m] = *(const bf16x8*)&As[cur][(wr * 64 + m * 16 + lrow) * 32 + lgrp * 8];
#pragma unroll
    for (int n = 0; n < 4; ++n)
      bfv[n] = *(const bf16x8*)&Bs[cur][(wc * 64 + n * 16 + lrow) * 32 + lgrp * 8];
    __builtin_amdgcn_s_setprio(1);
#pragma unroll
    for (int m = 0; m < 4; ++m)
#pragma unroll
      for (int n = 0; n < 4; ++n)
        acc[m][n] = __builtin_amdgcn_mfma_f32_16x16x32_bf16(af[m], bfv[n], acc[m][n], 0, 0, 0);
    __builtin_amdgcn_s_setprio(0);
    cur ^= 1;
  }

#pragma unroll
  for (int mi = 0; mi < 4; ++mi)
#pragma unroll
    for (int ni = 0; ni < 4; ++ni) {
      const int m = M0 + wr * 64 + mi * 16 + lgrp * 4;  // + r
      const int n = N0 + wc * 64 + ni * 16 + lrow;
      const int b = m >> 11, t = m & 2047;
      if (z < 2) {
        unsigned short* o = outp +
            ((size_t)(b * 16 + (n >> 6)) * 2048 + t) * 64 + (n & 63);
#pragma unroll
        for (int r = 0; r < 4; ++r) o[(size_t)r * 64] = f2b(acc[mi][ni][r]);
      } else {
        unsigned short* o = outp +
            ((size_t)(b * 16 + (n >> 6)) * 64 + (n & 63)) * 2048 + t;
        *(ushort4*)o = make_ushort4(f2b(acc[mi][ni][0]), f2b(acc[mi][ni][1]),
                                    f2b(acc[mi][ni][2]), f2b(acc[mi][ni][3]));
      }
    }
}

// ---------------- output projection GEMM: BM=64, dbuf, 1 barrier/K-step -------
__global__ __launch_bounds__(256) void gemm_o_k(const unsigned short* __restrict__ Ab,
                                                const unsigned short* __restrict__ Wp,
                                                float* __restrict__ outp) {
  __shared__ unsigned short As[2][64 * 32];
  __shared__ unsigned short Bs[2][128 * 32];
  const int M0 = blockIdx.x * 64, N0 = blockIdx.y * 128;
  const int tid = threadIdx.x, lane = tid & 63, w = tid >> 6;
  const int wr = w >> 1, wc = w & 1;
  const int lrow = lane & 15, lgrp = lane >> 4;

  const f32x4 Z4 = {0.f, 0.f, 0.f, 0.f};
  f32x4 acc[2][4];
#pragma unroll
  for (int i = 0; i < 2; ++i)
#pragma unroll
    for (int j = 0; j < 4; ++j) acc[i][j] = Z4;

  auto STAGE = [&](int bu, int kt) {
    {
      const unsigned short* gA = Ab +
          (size_t)(M0 + w * 16 + (lane >> 2)) * 1024 + kt + (lane & 3) * 8;
      gld16(gA, &As[bu][w * 512]);
    }
#pragma unroll
    for (int i = 0; i < 2; ++i) {
      const unsigned short* gB = Wp +
          (size_t)(N0 + i * 64 + w * 16 + (lane >> 2)) * 1024 + kt + (lane & 3) * 8;
      gld16(gB, &Bs[bu][i * 2048 + w * 512]);
    }
  };

  STAGE(0, 0);
  int cur = 0;
  for (int kt = 0; kt < 1024; kt += 32) {
    __syncthreads();
    if (kt + 32 < 1024) STAGE(cur ^ 1, kt + 32);
    bf16x8 af[2], bfv[4];
#pragma unroll
    for (int m = 0; m < 2; ++m)
      af[m] = *(const bf16x8*)&As[cur][(wr * 32 + m * 16 + lrow) * 32 + lgrp * 8];
#pragma unroll
    for (int n = 0; n < 4; ++n)
      bfv[n] = *(const bf16x8*)&Bs[cur][(wc * 64 + n * 16 + lrow) * 32 + lgrp * 8];
    __builtin_amdgcn_s_setprio(1);
#pragma unroll
    for (int m = 0; m < 2; ++m)
#pragma unroll
      for (int n = 0; n < 4; ++n)
        acc[m][n] = __builtin_amdgcn_mfma_f32_16x16x32_bf16(af[m], bfv[n], acc[m][n], 0, 0, 0);
    __builtin_amdgcn_s_setprio(0);
    cur ^= 1;
  }

#pragma unroll
  for (int mi = 0; mi < 2; ++mi)
#pragma unroll
    for (int ni = 0; ni < 4; ++ni) {
      const int m = M0 + wr * 32 + mi * 16 + lgrp * 4;  // + r
      const int n = N0 + wc * 64 + ni * 16 + lrow;
      float* o = outp + (size_t)m * 1024 + n;
#pragma unroll
      for (int r = 0; r < 4; ++r) o[(size_t)r * 1024] = acc[mi][ni][r];
    }
}

// ---------------- RoPE apply (in-place bf16, 4 elems/thread) -------------
__global__ void rope_apply_k(unsigned short* __restrict__ qh, unsigned short* __restrict__ kh,
                             const float* __restrict__ sin_t, const float* __restrict__ cos_t) {
  const size_t per = (size_t)2 * 16 * 2048 * 16;
  size_t gid = (size_t)blockIdx.x * blockDim.x + threadIdx.x;
  if (gid >= 2 * per) return;
  unsigned short* base = (gid < per) ? qh : kh;
  size_t g = (gid < per) ? gid : gid - per;
  const int t = (int)((g >> 4) & 2047);
  const int d0 = ((int)g & 15) * 4;
  ushort4 x = ((ushort4*)base)[g];
  const float4 s4 = *(const float4*)&sin_t[t * 64 + d0];
  const float4 c4 = *(const float4*)&cos_t[t * 64 + d0];
  float x0 = b2f(x.x), x1 = b2f(x.y), x2 = b2f(x.z), x3 = b2f(x.w);
  ushort4 o;
  o.x = f2b(x0 * c4.x - x1 * s4.x);
  o.y = f2b(x1 * c4.y + x0 * s4.y);
  o.z = f2b(x2 * c4.z - x3 * s4.z);
  o.w = f2b(x3 * c4.w + x2 * s4.w);
  ((ushort4*)base)[g] = o;
}

// ---------------- Flash attention: 2-wave blocks, balanced-CU decode ----------
// Wave-level code identical to round 12 (S^T = mfma(K,Q), log2 defer-max
// softmax, O^T = mfma(V,P), XOR-swizzled LDS, 1 barrier/step).  Block = 128
// threads / 64 q-rows; 1024 blocks = 4/CU.  Decode gives each CU four blocks
// of the SAME bh with tile-steps summing to a constant 66 (perfect balance +
// L2 sharing); heavy tiles dispatch first.
__global__ __launch_bounds__(128, 2) void attn_k(
    const unsigned short* __restrict__ qh, const unsigned short* __restrict__ kh,
    const unsigned short* __restrict__ vt, const unsigned long long* __restrict__ pmask,
    unsigned short* __restrict__ ao) {
  const int bid = blockIdx.x;
  const int x = bid & 7, j = bid >> 3;
  const int bh = x * 4 + (j & 3);
  const int ti = j >> 2;                 // tau_idx in [0,32)
  const int r_ = ti >> 3, p_ = ti & 7;
  const int tau = 31 - (r_ * 8 + ((r_ & 1) ? (7 - p_) : p_));
  const int b = bh >> 4, h = bh & 15;
  const int tid = threadIdx.x, lane = tid & 63, w = tid >> 6;   // w in {0,1}
  const int ln31 = lane & 31, hi = lane >> 5;

  __shared__ char Kb[2][8192];
  __shared__ char Vb[2][8192];
  __shared__ int flagv;

  const size_t bh_off = (size_t)bh * 2048 * 64;
  const int qw = tau * 64 + w * 32;
  const int q_abs = qw + ln31;
  const int nkv_w = qw / 64 + 1;
  const int nkv_b = tau + 1;
  const int swz = (ln31 & 7) << 4;

  bf16x8 qf[4];
#pragma unroll
  for (int dc = 0; dc < 4; ++dc)
    qf[dc] = *(const bf16x8*)(qh + bh_off + (size_t)(qw + ln31) * 64 + dc * 16 + hi * 8);

  const f32x16 Z16 = {0.f,0.f,0.f,0.f,0.f,0.f,0.f,0.f,0.f,0.f,0.f,0.f,0.f,0.f,0.f,0.f};
  f32x16 O0 = Z16, O1 = Z16;
  float m_run = -INFINITY, l_run = 0.f;

  // staging with 128 threads: 64 B/thread for K and for V (4x uint4 each)
  uint4 kr0, kr1, kr2, kr3, vr0, vr1, vr2, vr3;
  const int srow = tid >> 1, sseg = tid & 1;
  const int kbase = srow * 128 + sseg * 64;
  const int sswz = (srow & 7) << 4;

  auto stage_load = [&](int kbi) {
    const unsigned short* kp = kh + bh_off + (size_t)(kbi * 64 + srow) * 64 + sseg * 32;
    kr0 = *(const uint4*)kp;        kr1 = *(const uint4*)(kp + 8);
    kr2 = *(const uint4*)(kp + 16); kr3 = *(const uint4*)(kp + 24);
    const unsigned short* vp = vt + bh_off + (size_t)srow * 2048 + kbi * 64 + sseg * 32;
    vr0 = *(const uint4*)vp;        vr1 = *(const uint4*)(vp + 8);
    vr2 = *(const uint4*)(vp + 16); vr3 = *(const uint4*)(vp + 24);
  };
  auto stage_write = [&](int bu) {
    *(uint4*)(Kb[bu] + ((kbase)      ^ sswz)) = kr0;
    *(uint4*)(Kb[bu] + ((kbase + 16) ^ sswz)) = kr1;
    *(uint4*)(Kb[bu] + ((kbase + 32) ^ sswz)) = kr2;
    *(uint4*)(Kb[bu] + ((kbase + 48) ^ sswz)) = kr3;
    *(uint4*)(Vb[bu] + ((kbase)      ^ sswz)) = vr0;
    *(uint4*)(Vb[bu] + ((kbase + 16) ^ sswz)) = vr1;
    *(uint4*)(Vb[bu] + ((kbase + 32) ^ sswz)) = vr2;
    *(uint4*)(Vb[bu] + ((kbase + 48) ^ sswz)) = vr3;
  };

  auto compute = [&](int kb, int cur) {
    const unsigned long long pmh = pmask[b * 32 + kb] >> (hi * 4);
    f32x16 S0 = Z16, S1 = Z16;
    __builtin_amdgcn_s_setprio(1);
#pragma unroll
    for (int dc = 0; dc < 4; ++dc) {
      bf16x8 k0 = *(const bf16x8*)(Kb[cur] + ((ln31 * 128 + dc * 32 + hi * 16) ^ swz));
      bf16x8 k1 = *(const bf16x8*)(Kb[cur] + (((ln31 + 32) * 128 + dc * 32 + hi * 16) ^ swz));
      S0 = __builtin_amdgcn_mfma_f32_32x32x16_bf16(k0, qf[dc], S0, 0, 0, 0);
      S1 = __builtin_amdgcn_mfma_f32_32x32x16_bf16(k1, qf[dc], S1, 0, 0, 0);
    }
    __builtin_amdgcn_s_setprio(0);

    const bool diag = (kb * 64 + 63) > qw;
    if (diag) {
#pragma unroll
      for (int r = 0; r < 16; ++r) {
        const int kloc = (r & 3) + 8 * (r >> 2);
        float sv = S0[r] * SC_LOG2;
        sv = ((pmh >> kloc) & 1) ? NEG_BIG2
             : ((kb * 64 + kloc + 4 * hi > q_abs) ? sv + NEG_BIG2 : sv);
        S0[r] = sv;
        float sw = S1[r] * SC_LOG2;
        sw = ((pmh >> (kloc + 32)) & 1) ? NEG_BIG2
             : ((kb * 64 + 32 + kloc + 4 * hi > q_abs) ? sw + NEG_BIG2 : sw);
        S1[r] = sw;
      }
    } else {
#pragma unroll
      for (int r = 0; r < 16; ++r) {
        const int kloc = (r & 3) + 8 * (r >> 2);
        float sv = S0[r] * SC_LOG2;
        S0[r] = ((pmh >> kloc) & 1) ? NEG_BIG2 : sv;
        float sw = S1[r] * SC_LOG2;
        S1[r] = ((pmh >> (kloc + 32)) & 1) ? NEG_BIG2 : sw;
      }
    }

    float vm = fmaxf(S0[0], S0[1]);
#pragma unroll
    for (int r = 2; r < 16; r += 2) vm = fmaxf(vm, fmaxf(S0[r], S0[r + 1]));
#pragma unroll
    for (int r = 0; r < 16; r += 2) vm = fmaxf(vm, fmaxf(S1[r], S1[r + 1]));
    vm = fmaxf(vm, __shfl_xor(vm, 32));

    if (__any(vm > m_run + 11.5f)) {
      const float mnew = fmaxf(m_run, vm);
      const float alpha = ex2(m_run - mnew);
      m_run = mnew;
      l_run *= alpha;
      O0 *= alpha; O1 *= alpha;
    }
    float rs = 0.f;
#pragma unroll
    for (int r = 0; r < 16; ++r) { float p = ex2(S0[r] - m_run); S0[r] = p; rs += p; }
#pragma unroll
    for (int r = 0; r < 16; ++r) { float p = ex2(S1[r] - m_run); S1[r] = p; rs += p; }
    rs += __shfl_xor(rs, 32);
    l_run += rs;

    union U8 { uint4 u; bf16x8 v; };
    bf16x8 pa[4];
#pragma unroll
    for (int kt = 0; kt < 2; ++kt) {
#pragma unroll
      for (int hf = 0; hf < 2; ++hf) {
        float p0, p1, p2, p3, p4, p5, p6, p7;
        if (kt == 0) {
          if (hf == 0) { p0=S0[0];p1=S0[1];p2=S0[2];p3=S0[3];p4=S0[4];p5=S0[5];p6=S0[6];p7=S0[7]; }
          else         { p0=S0[8];p1=S0[9];p2=S0[10];p3=S0[11];p4=S0[12];p5=S0[13];p6=S0[14];p7=S0[15]; }
        } else {
          if (hf == 0) { p0=S1[0];p1=S1[1];p2=S1[2];p3=S1[3];p4=S1[4];p5=S1[5];p6=S1[6];p7=S1[7]; }
          else         { p0=S1[8];p1=S1[9];p2=S1[10];p3=S1[11];p4=S1[12];p5=S1[13];p6=S1[14];p7=S1[15]; }
        }
        unsigned e0 = pk2(p0, p1), e1 = pk2(p2, p3);
        unsigned o0 = pk2(p4, p5), o1 = pk2(p6, p7);
        unsigned a0, b0_, a1, b1_;
        swap_pair(e0, o0, hi, a0, b0_);
        swap_pair(e1, o1, hi, a1, b1_);
        U8 u; u.u = make_uint4(a0, a1, b0_, b1_);
        pa[kt * 2 + hf] = u.v;
      }
    }

    __builtin_amdgcn_s_setprio(1);
#pragma unroll
    for (int c = 0; c < 4; ++c) {
      bf16x8 v0 = *(const bf16x8*)(Vb[cur] + ((ln31 * 128 + c * 32 + hi * 16) ^ swz));
      bf16x8 v1 = *(const bf16x8*)(Vb[cur] + (((ln31 + 32) * 128 + c * 32 + hi * 16) ^ swz));
      O0 = __builtin_amdgcn_mfma_f32_32x32x16_bf16(v0, pa[c], O0, 0, 0, 0);
      O1 = __builtin_amdgcn_mfma_f32_32x32x16_bf16(v1, pa[c], O1, 0, 0, 0);
    }
    __builtin_amdgcn_s_setprio(0);
  };

  // main causal loop: double-buffered, ONE barrier per step (round-12 proof)
  stage_load(0);
  stage_write(0);
  for (int kb = 0; kb < nkv_b; ++kb) {
    if (kb + 1 < nkv_b) stage_load(kb + 1);
    __syncthreads();
    if (kb < nkv_w) compute(kb, kb & 1);
    if (kb + 1 < nkv_b) stage_write((kb + 1) & 1);
  }

  // pathological rows (entire visible prefix padded): extend over all keys
  if (tid == 0) flagv = 0;
  __syncthreads();
  if (m_run <= -7.2e8f) flagv = 1;
  __syncthreads();
  if (flagv) {
    for (int kb = nkv_b - 1; kb < 32; ++kb) {
      if (kb + 1 < 32) stage_load(kb + 1);
      __syncthreads();
      if (kb >= nkv_w) compute(kb, kb & 1);
      if (kb + 1 < 32) stage_write((kb + 1) & 1);
    }
  }

  // epilogue: O0[r] = O[d=(r&3)+8*(r>>2)+4*hi][q=qw+ln31]; lane owns row q.
  {
    const float inv = 1.0f / l_run;
    unsigned short* op = ao + (size_t)(b * 2048 + qw + ln31) * 1024 + h * 64;
#pragma unroll
    for (int g2 = 0; g2 < 4; ++g2) {
      const int d0 = 8 * g2 + 4 * hi;
      *(ushort4*)(op + d0) = make_ushort4(
          f2b(O0[g2 * 4 + 0] * inv), f2b(O0[g2 * 4 + 1] * inv),
          f2b(O0[g2 * 4 + 2] * inv), f2b(O0[g2 * 4 + 3] * inv));
      *(ushort4*)(op + 32 + d0) = make_ushort4(
          f2b(O1[g2 * 4 + 0] * inv), f2b(O1[g2 * 4 + 1] * inv),
          f2b(O1[g2 * 4 + 2] * inv), f2b(O1[g2 * 4 + 3] * inv));
    }
  }
}

extern "C" void kernel_launch(void* const* d_in, const int* in_sizes, int n_in,
                              void* d_out, int out_size, void* d_ws, size_t ws_size,
                              hipStream_t stream) {
  const float* q  = (const float*)d_in[0];
  const float* k  = (const float*)d_in[1];
  const float* v  = (const float*)d_in[2];
  const void*  kpm = d_in[4];
  const float* Wq = (const float*)d_in[5];
  const float* Wk = (const float*)d_in[6];
  const float* Wv = (const float*)d_in[7];
  const float* Wo = (const float*)d_in[8];

  char* ws = (char*)d_ws;
  unsigned short* qh = (unsigned short*)(ws);                       // 8 MB (b,h,t,d)
  unsigned short* kh = (unsigned short*)(ws + (8u << 20));          // 8 MB
  unsigned short* vt = (unsigned short*)(ws + (16u << 20));         // 8 MB (b,h,d,t)
  unsigned short* ao = (unsigned short*)(ws + (24u << 20));         // 8 MB (B*T, D)
  unsigned short* Wb = (unsigned short*)(ws + (32u << 20));         // 8 MB (4 x 1M)
  float* sin_t = (float*)(ws + (40u << 20));                        // 512 KB
  float* cos_t = (float*)(ws + (40u << 20) + 524288);               // 512 KB
  unsigned long long* pmask = (unsigned long long*)(ws + (41u << 20));  // 512 B
  int* mflag = (int*)(ws + (41u << 20) + 512);
  unsigned short* qb = (unsigned short*)(ws + (42u << 20));         // 8 MB bf16 q
  unsigned short* kb = (unsigned short*)(ws + (50u << 20));         // 8 MB bf16 k
  unsigned short* vb = (unsigned short*)(ws + (58u << 20));         // 8 MB bf16 v

  const bool big = ws_size >= (66ull << 20);

  (void)hipMemsetAsync(mflag, 0, sizeof(int), stream);
  detect_mask_k<<<1, 256, 0, stream>>>((const unsigned int*)kpm, mflag);
  mask_pack_k<<<1, 256, 0, stream>>>(kpm, mflag, pmask);
  rope_table_k<<<512, 256, 0, stream>>>(sin_t, cos_t);
  convw_k<<<2048, 256, 0, stream>>>(Wq, Wk, Wv, Wo, Wb);

  dim3 gq(32, 8, 3);
  if (big) {
    conv_in_k<<<6144, 256, 0, stream>>>(q, k, v, qb, kb, vb);
    qkv_k<true><<<gq, 256, 0, stream>>>(qb, kb, vb, Wb, qh, kh, vt);
  } else {
    qkv_k<false><<<gq, 256, 0, stream>>>(q, k, v, Wb, qh, kh, vt);
  }

  rope_apply_k<<<8192, 256, 0, stream>>>(qh, kh, sin_t, cos_t);

  attn_k<<<1024, 128, 0, stream>>>(qh, kh, vt, pmask, ao);

  gemm_o_k<<<dim3(64, 8), 256, 0, stream>>>(ao, Wb + 3145728, (float*)d_out);
}

// Round 14
// 146.616 us; speedup vs baseline: 1.0621x; 1.0621x over previous
//
#include <hip/hip_runtime.h>
#include <stdint.h>

typedef __bf16 bf16x8 __attribute__((ext_vector_type(8)));
typedef float f32x4 __attribute__((ext_vector_type(4)));
typedef float f32x16 __attribute__((ext_vector_type(16)));

#define NEG_BIG2 (-1.442695040e9f)      // -1e9 * log2(e)
#define SC_LOG2  (0.180336880f)         // 0.125 * log2(e)

__device__ __forceinline__ unsigned short f2b(float f) {
  union { float f; unsigned int u; } c; c.f = f;
  unsigned int u = c.u;
  u += 0x7FFFu + ((u >> 16) & 1u);
  return (unsigned short)(u >> 16);
}
__device__ __forceinline__ float b2f(unsigned short h) {
  union { unsigned int u; float f; } c; c.u = ((unsigned int)h) << 16;
  return c.f;
}
__device__ __forceinline__ unsigned int pk2(float a, float b) {
  __bf16 x = (__bf16)a, y = (__bf16)b;
  unsigned short xu, yu;
  __builtin_memcpy(&xu, &x, 2);
  __builtin_memcpy(&yu, &y, 2);
  return (unsigned)xu | ((unsigned)yu << 16);
}
// raw v_exp_f32: D = 2^x
__device__ __forceinline__ float ex2(float x) {
  float r; asm("v_exp_f32 %0, %1" : "=v"(r) : "v"(x)); return r;
}

// global -> LDS direct (16B per lane)
typedef const __attribute__((address_space(1))) unsigned int ga_u32;
typedef __attribute__((address_space(3))) unsigned int ls_u32;
__device__ __forceinline__ void gld16(const void* g, void* l) {
  __builtin_amdgcn_global_load_lds((ga_u32*)g, (ls_u32*)l, 16, 0, 0);
}

__device__ __forceinline__ void swap_pair(unsigned a, unsigned b, int hi,
                                          unsigned& lo_out, unsigned& hi_out) {
#if __has_builtin(__builtin_amdgcn_permlane32_swap)
  auto r = __builtin_amdgcn_permlane32_swap(a, b, false, false);
  lo_out = r[0]; hi_out = r[1];
#else
  unsigned pa = __shfl_xor(a, 32), pb = __shfl_xor(b, 32);
  lo_out = hi ? pb : a;
  hi_out = hi ? b : pa;
#endif
}

// ---------------- RoPE sin/cos table (T x 64) ----------------
__global__ void rope_table_k(float* __restrict__ sin_t, float* __restrict__ cos_t) {
  int i = blockIdx.x * blockDim.x + threadIdx.x;  // 2048*64
  int t = i >> 6, d = i & 63, f = d & 31;
  double inv = exp(-((double)(2 * f) / 64.0) * log(10000.0));
  double ang = (double)t * inv;
  sin_t[i] = (float)sin(ang);
  cos_t[i] = (float)cos(ang);
}

// ---------------- key_padding_mask dtype detector ----------------
__global__ void detect_mask_k(const unsigned int* __restrict__ kpm, int* __restrict__ flag) {
  unsigned int v = 0;
  for (int i = threadIdx.x; i < 1024; i += 256) v |= kpm[i];
  if (v & ~1u) atomicOr(flag, 1);
}

// ---------------- pack key_padding_mask into per-(b, kv64) 64-bit masks -------
__global__ void mask_pack_k(const void* __restrict__ kpm, const int* __restrict__ mflag,
                            unsigned long long* __restrict__ pmask) {
  const int w = threadIdx.x >> 6, lane = threadIdx.x & 63;
  const int bytes = *mflag;
  for (int i = w; i < 64; i += 4) {
    int b = i >> 5, kb = i & 31;
    int idx = b * 2048 + kb * 64 + lane;
    int pad = bytes ? (int)((const unsigned char*)kpm)[idx] : ((const int*)kpm)[idx];
    unsigned long long pm = __ballot(pad != 0);
    if (lane == 0) pmask[i] = pm;
  }
}

// ---------------- convert 4 weight matrices fp32 -> bf16 ----------------------
__global__ void convw_k(const float* __restrict__ Wq, const float* __restrict__ Wk,
                        const float* __restrict__ Wv, const float* __restrict__ Wo,
                        unsigned short* __restrict__ Wb) {
  size_t g = (size_t)blockIdx.x * 256 + threadIdx.x;
  size_t i8 = g * 8;
  int t = (int)(i8 >> 20);
  const float* src = (t == 0 ? Wq : t == 1 ? Wk : t == 2 ? Wv : Wo) + (i8 & 1048575);
  float4 a = *(const float4*)src, c = *(const float4*)(src + 4);
  uint4 o = { pk2(a.x, a.y), pk2(a.z, a.w), pk2(c.x, c.y), pk2(c.z, c.w) };
  *(uint4*)&Wb[i8] = o;
}

// ---------------- convert q,k,v fp32 -> bf16 ------------------
__global__ void conv_in_k(const float* __restrict__ q, const float* __restrict__ k,
                          const float* __restrict__ v, unsigned short* __restrict__ qb,
                          unsigned short* __restrict__ kb, unsigned short* __restrict__ vb) {
  size_t g = (size_t)blockIdx.x * 256 + threadIdx.x;  // 8-elem groups
  size_t i8 = g * 8;
  int t = (int)(i8 >> 22);
  size_t off = i8 & 4194303;
  const float* src = (t == 0 ? q : t == 1 ? k : v) + off;
  unsigned short* dst = (t == 0 ? qb : t == 1 ? kb : vb) + off;
  float4 a = *(const float4*)src, c = *(const float4*)(src + 4);
  uint4 o = { pk2(a.x, a.y), pk2(a.z, a.w), pk2(c.x, c.y), pk2(c.z, c.w) };
  *(uint4*)dst = o;
}

// ---------------- fused QKV projection GEMM (grid.z selects q/k/v) ------------
// z=0 -> qh (b,h,t,d) with RoPE fused into the epilogue
// z=1 -> kh (b,h,t,d) with RoPE fused
// z=2 -> vt (b,h,d,t), no RoPE
// RoPE fusion: column d = n&63 has d&1 == lane&1, so the rotate-half partner
// x[d^1] is __shfl_xor(x, 1) (same fragment register, adjacent lane).  Applied
// on the fp32 accumulator BEFORE the single bf16 round (closer to fp32 ref
// than the old bf16->rope->bf16 pass).  Double-buffered LDS, 1 barrier/K-step.
template<bool ABF>
__global__ __launch_bounds__(256) void qkv_k(const void* __restrict__ A0,
                                             const void* __restrict__ A1,
                                             const void* __restrict__ A2,
                                             const unsigned short* __restrict__ Wb,
                                             const float* __restrict__ sin_t,
                                             const float* __restrict__ cos_t,
                                             unsigned short* __restrict__ qh,
                                             unsigned short* __restrict__ kh,
                                             unsigned short* __restrict__ vt) {
  const int z = blockIdx.z;
  const void* Ap = (z == 0) ? A0 : (z == 1) ? A1 : A2;
  const unsigned short* Wp = Wb + (size_t)z * 1048576;
  unsigned short* outp = (z == 0) ? qh : (z == 1) ? kh : vt;

  __shared__ unsigned short As[2][128 * 32];
  __shared__ unsigned short Bs[2][128 * 32];
  const int M0 = blockIdx.x * 128, N0 = blockIdx.y * 128;
  const int tid = threadIdx.x, lane = tid & 63, w = tid >> 6;
  const int wr = w >> 1, wc = w & 1;
  const int lrow = lane & 15, lgrp = lane >> 4;

  const f32x4 Z4 = {0.f, 0.f, 0.f, 0.f};
  f32x4 acc[4][4];
#pragma unroll
  for (int i = 0; i < 4; ++i)
#pragma unroll
    for (int j = 0; j < 4; ++j) acc[i][j] = Z4;

  auto STAGE = [&](int bu, int kt) {
    if (ABF) {
      const unsigned short* Ab = (const unsigned short*)Ap;
#pragma unroll
      for (int i = 0; i < 2; ++i) {
        const unsigned short* gA = Ab +
            (size_t)(M0 + i * 64 + w * 16 + (lane >> 2)) * 1024 + kt + (lane & 3) * 8;
        gld16(gA, &As[bu][i * 2048 + w * 512]);
      }
    } else {
      const int row = tid >> 1, half = tid & 1;
      const float* ap = (const float*)Ap + (size_t)(M0 + row) * 1024 + kt + half * 16;
      float4 f0 = *(const float4*)ap, f1 = *(const float4*)(ap + 4);
      float4 f2 = *(const float4*)(ap + 8), f3 = *(const float4*)(ap + 12);
      uint4 u0 = { pk2(f0.x, f0.y), pk2(f0.z, f0.w), pk2(f1.x, f1.y), pk2(f1.z, f1.w) };
      uint4 u1 = { pk2(f2.x, f2.y), pk2(f2.z, f2.w), pk2(f3.x, f3.y), pk2(f3.z, f3.w) };
      *(uint4*)&As[bu][row * 32 + half * 16] = u0;
      *(uint4*)&As[bu][row * 32 + half * 16 + 8] = u1;
    }
#pragma unroll
    for (int i = 0; i < 2; ++i) {
      const unsigned short* gB = Wp +
          (size_t)(N0 + i * 64 + w * 16 + (lane >> 2)) * 1024 + kt + (lane & 3) * 8;
      gld16(gB, &Bs[bu][i * 2048 + w * 512]);
    }
  };

  STAGE(0, 0);
  int cur = 0;
  for (int kt = 0; kt < 1024; kt += 32) {
    __syncthreads();
    if (kt + 32 < 1024) STAGE(cur ^ 1, kt + 32);
    bf16x8 af[4], bfv[4];
#pragma unroll
    for (int m = 0; m < 4; ++m)
      af[m] = *(const bf16x8*)&As[cur][(wr * 64 + m * 16 + lrow) * 32 + lgrp * 8];
#pragma unroll
    for (int n = 0; n < 4; ++n)
      bfv[n] = *(const bf16x8*)&Bs[cur][(wc * 64 + n * 16 + lrow) * 32 + lgrp * 8];
    __builtin_amdgcn_s_setprio(1);
#pragma unroll
    for (int m = 0; m < 4; ++m)
#pragma unroll
      for (int n = 0; n < 4; ++n)
        acc[m][n] = __builtin_amdgcn_mfma_f32_16x16x32_bf16(af[m], bfv[n], acc[m][n], 0, 0, 0);
    __builtin_amdgcn_s_setprio(0);
    cur ^= 1;
  }

#pragma unroll
  for (int mi = 0; mi < 4; ++mi)
#pragma unroll
    for (int ni = 0; ni < 4; ++ni) {
      const int m = M0 + wr * 64 + mi * 16 + lgrp * 4;  // + r
      const int n = N0 + wc * 64 + ni * 16 + lrow;
      const int b = m >> 11, t = m & 2047;
      const int d = n & 63;
      if (z < 2) {
        unsigned short* o = outp +
            ((size_t)(b * 16 + (n >> 6)) * 2048 + t) * 64 + d;
#pragma unroll
        for (int r = 0; r < 4; ++r) {
          const float xv = acc[mi][ni][r];
          const float pr = __shfl_xor(xv, 1);         // x[d^1], same row
          const int tt = t + r;
          const float cs = cos_t[tt * 64 + d];
          const float sn = sin_t[tt * 64 + d];
          const float ov = xv * cs + ((d & 1) ? pr : -pr) * sn;
          o[(size_t)r * 64] = f2b(ov);
        }
      } else {
        unsigned short* o = outp +
            ((size_t)(b * 16 + (n >> 6)) * 64 + d) * 2048 + t;
        *(ushort4*)o = make_ushort4(f2b(acc[mi][ni][0]), f2b(acc[mi][ni][1]),
                                    f2b(acc[mi][ni][2]), f2b(acc[mi][ni][3]));
      }
    }
}

// ---------------- output projection GEMM: BM=64, dbuf, 1 barrier/K-step -------
__global__ __launch_bounds__(256) void gemm_o_k(const unsigned short* __restrict__ Ab,
                                                const unsigned short* __restrict__ Wp,
                                                float* __restrict__ outp) {
  __shared__ unsigned short As[2][64 * 32];
  __shared__ unsigned short Bs[2][128 * 32];
  const int M0 = blockIdx.x * 64, N0 = blockIdx.y * 128;
  const int tid = threadIdx.x, lane = tid & 63, w = tid >> 6;
  const int wr = w >> 1, wc = w & 1;
  const int lrow = lane & 15, lgrp = lane >> 4;

  const f32x4 Z4 = {0.f, 0.f, 0.f, 0.f};
  f32x4 acc[2][4];
#pragma unroll
  for (int i = 0; i < 2; ++i)
#pragma unroll
    for (int j = 0; j < 4; ++j) acc[i][j] = Z4;

  auto STAGE = [&](int bu, int kt) {
    {
      const unsigned short* gA = Ab +
          (size_t)(M0 + w * 16 + (lane >> 2)) * 1024 + kt + (lane & 3) * 8;
      gld16(gA, &As[bu][w * 512]);
    }
#pragma unroll
    for (int i = 0; i < 2; ++i) {
      const unsigned short* gB = Wp +
          (size_t)(N0 + i * 64 + w * 16 + (lane >> 2)) * 1024 + kt + (lane & 3) * 8;
      gld16(gB, &Bs[bu][i * 2048 + w * 512]);
    }
  };

  STAGE(0, 0);
  int cur = 0;
  for (int kt = 0; kt < 1024; kt += 32) {
    __syncthreads();
    if (kt + 32 < 1024) STAGE(cur ^ 1, kt + 32);
    bf16x8 af[2], bfv[4];
#pragma unroll
    for (int m = 0; m < 2; ++m)
      af[m] = *(const bf16x8*)&As[cur][(wr * 32 + m * 16 + lrow) * 32 + lgrp * 8];
#pragma unroll
    for (int n = 0; n < 4; ++n)
      bfv[n] = *(const bf16x8*)&Bs[cur][(wc * 64 + n * 16 + lrow) * 32 + lgrp * 8];
    __builtin_amdgcn_s_setprio(1);
#pragma unroll
    for (int m = 0; m < 2; ++m)
#pragma unroll
      for (int n = 0; n < 4; ++n)
        acc[m][n] = __builtin_amdgcn_mfma_f32_16x16x32_bf16(af[m], bfv[n], acc[m][n], 0, 0, 0);
    __builtin_amdgcn_s_setprio(0);
    cur ^= 1;
  }

#pragma unroll
  for (int mi = 0; mi < 2; ++mi)
#pragma unroll
    for (int ni = 0; ni < 4; ++ni) {
      const int m = M0 + wr * 32 + mi * 16 + lgrp * 4;  // + r
      const int n = N0 + wc * 64 + ni * 16 + lrow;
      float* o = outp + (size_t)m * 1024 + n;
#pragma unroll
      for (int r = 0; r < 4; ++r) o[(size_t)r * 1024] = acc[mi][ni][r];
    }
}

// ---------------- Flash attention (round-12 verbatim: best measured) ----------
// S^T = mfma(K, Q): q on C/D COLUMN (lane&31); log2-domain defer-max softmax.
// O^T = mfma(V, P).  Double-buffered, ONE barrier per KV step.
__global__ __launch_bounds__(256, 2) void attn_k(
    const unsigned short* __restrict__ qh, const unsigned short* __restrict__ kh,
    const unsigned short* __restrict__ vt, const unsigned long long* __restrict__ pmask,
    unsigned short* __restrict__ ao) {
  // work-descending + XCD-grouped decode: 512 blocks
  const int bid = blockIdx.x;
  const int x = bid & 7, g = bid >> 3;
  const int bh = x * 4 + (g & 3);
  const int tile = 15 - (g >> 2);
  const int b = bh >> 4, h = bh & 15;
  const int tid = threadIdx.x, lane = tid & 63, w = tid >> 6;
  const int ln31 = lane & 31, hi = lane >> 5;

  __shared__ char Kb[2][8192];
  __shared__ char Vb[2][8192];
  __shared__ int flagv;

  const size_t bh_off = (size_t)bh * 2048 * 64;
  const int qw = tile * 128 + w * 32;
  const int q_abs = qw + ln31;
  const int nkv_w = qw / 64 + 1;
  const int nkv_b = tile * 2 + 2;
  const int swz = (ln31 & 7) << 4;

  bf16x8 qf[4];
#pragma unroll
  for (int dc = 0; dc < 4; ++dc)
    qf[dc] = *(const bf16x8*)(qh + bh_off + (size_t)(qw + ln31) * 64 + dc * 16 + hi * 8);

  const f32x16 Z16 = {0.f,0.f,0.f,0.f,0.f,0.f,0.f,0.f,0.f,0.f,0.f,0.f,0.f,0.f,0.f,0.f};
  f32x16 O0 = Z16, O1 = Z16;
  float m_run = -INFINITY, l_run = 0.f;

  uint4 kr0, kr1, vr0, vr1;
  const int srow = tid >> 2, sseg = tid & 3;
  const int sbase = srow * 128 + sseg * 32;
  const int sswz = (srow & 7) << 4;

  auto stage_load = [&](int kbi) {
    const unsigned short* kp = kh + bh_off + (size_t)(kbi * 64 + srow) * 64 + sseg * 16;
    kr0 = *(const uint4*)kp; kr1 = *(const uint4*)(kp + 8);
    const unsigned short* vp = vt + bh_off + (size_t)srow * 2048 + kbi * 64 + sseg * 16;
    vr0 = *(const uint4*)vp; vr1 = *(const uint4*)(vp + 8);
  };
  auto stage_write = [&](int bu) {
    *(uint4*)(Kb[bu] + (sbase ^ sswz)) = kr0;
    *(uint4*)(Kb[bu] + ((sbase + 16) ^ sswz)) = kr1;
    *(uint4*)(Vb[bu] + (sbase ^ sswz)) = vr0;
    *(uint4*)(Vb[bu] + ((sbase + 16) ^ sswz)) = vr1;
  };

  auto compute = [&](int kb, int cur) {
    const unsigned long long pmh = pmask[b * 32 + kb] >> (hi * 4);
    f32x16 S0 = Z16, S1 = Z16;
    __builtin_amdgcn_s_setprio(1);
#pragma unroll
    for (int dc = 0; dc < 4; ++dc) {
      bf16x8 k0 = *(const bf16x8*)(Kb[cur] + ((ln31 * 128 + dc * 32 + hi * 16) ^ swz));
      bf16x8 k1 = *(const bf16x8*)(Kb[cur] + (((ln31 + 32) * 128 + dc * 32 + hi * 16) ^ swz));
      S0 = __builtin_amdgcn_mfma_f32_32x32x16_bf16(k0, qf[dc], S0, 0, 0, 0);
      S1 = __builtin_amdgcn_mfma_f32_32x32x16_bf16(k1, qf[dc], S1, 0, 0, 0);
    }
    __builtin_amdgcn_s_setprio(0);

    const bool diag = (kb * 64 + 63) > qw;
    if (diag) {
#pragma unroll
      for (int r = 0; r < 16; ++r) {
        const int kloc = (r & 3) + 8 * (r >> 2);
        float sv = S0[r] * SC_LOG2;
        sv = ((pmh >> kloc) & 1) ? NEG_BIG2
             : ((kb * 64 + kloc + 4 * hi > q_abs) ? sv + NEG_BIG2 : sv);
        S0[r] = sv;
        float sw = S1[r] * SC_LOG2;
        sw = ((pmh >> (kloc + 32)) & 1) ? NEG_BIG2
             : ((kb * 64 + 32 + kloc + 4 * hi > q_abs) ? sw + NEG_BIG2 : sw);
        S1[r] = sw;
      }
    } else {
#pragma unroll
      for (int r = 0; r < 16; ++r) {
        const int kloc = (r & 3) + 8 * (r >> 2);
        float sv = S0[r] * SC_LOG2;
        S0[r] = ((pmh >> kloc) & 1) ? NEG_BIG2 : sv;
        float sw = S1[r] * SC_LOG2;
        S1[r] = ((pmh >> (kloc + 32)) & 1) ? NEG_BIG2 : sw;
      }
    }

    float vm = fmaxf(S0[0], S0[1]);
#pragma unroll
    for (int r = 2; r < 16; r += 2) vm = fmaxf(vm, fmaxf(S0[r], S0[r + 1]));
#pragma unroll
    for (int r = 0; r < 16; r += 2) vm = fmaxf(vm, fmaxf(S1[r], S1[r + 1]));
    vm = fmaxf(vm, __shfl_xor(vm, 32));

    if (__any(vm > m_run + 11.5f)) {
      const float mnew = fmaxf(m_run, vm);
      const float alpha = ex2(m_run - mnew);
      m_run = mnew;
      l_run *= alpha;
      O0 *= alpha; O1 *= alpha;
    }
    float rs = 0.f;
#pragma unroll
    for (int r = 0; r < 16; ++r) { float p = ex2(S0[r] - m_run); S0[r] = p; rs += p; }
#pragma unroll
    for (int r = 0; r < 16; ++r) { float p = ex2(S1[r] - m_run); S1[r] = p; rs += p; }
    rs += __shfl_xor(rs, 32);
    l_run += rs;

    union U8 { uint4 u; bf16x8 v; };
    bf16x8 pa[4];
#pragma unroll
    for (int kt = 0; kt < 2; ++kt) {
#pragma unroll
      for (int hf = 0; hf < 2; ++hf) {
        float p0, p1, p2, p3, p4, p5, p6, p7;
        if (kt == 0) {
          if (hf == 0) { p0=S0[0];p1=S0[1];p2=S0[2];p3=S0[3];p4=S0[4];p5=S0[5];p6=S0[6];p7=S0[7]; }
          else         { p0=S0[8];p1=S0[9];p2=S0[10];p3=S0[11];p4=S0[12];p5=S0[13];p6=S0[14];p7=S0[15]; }
        } else {
          if (hf == 0) { p0=S1[0];p1=S1[1];p2=S1[2];p3=S1[3];p4=S1[4];p5=S1[5];p6=S1[6];p7=S1[7]; }
          else         { p0=S1[8];p1=S1[9];p2=S1[10];p3=S1[11];p4=S1[12];p5=S1[13];p6=S1[14];p7=S1[15]; }
        }
        unsigned e0 = pk2(p0, p1), e1 = pk2(p2, p3);
        unsigned o0 = pk2(p4, p5), o1 = pk2(p6, p7);
        unsigned a0, b0_, a1, b1_;
        swap_pair(e0, o0, hi, a0, b0_);
        swap_pair(e1, o1, hi, a1, b1_);
        U8 u; u.u = make_uint4(a0, a1, b0_, b1_);
        pa[kt * 2 + hf] = u.v;
      }
    }

    __builtin_amdgcn_s_setprio(1);
#pragma unroll
    for (int c = 0; c < 4; ++c) {
      bf16x8 v0 = *(const bf16x8*)(Vb[cur] + ((ln31 * 128 + c * 32 + hi * 16) ^ swz));
      bf16x8 v1 = *(const bf16x8*)(Vb[cur] + (((ln31 + 32) * 128 + c * 32 + hi * 16) ^ swz));
      O0 = __builtin_amdgcn_mfma_f32_32x32x16_bf16(v0, pa[c], O0, 0, 0, 0);
      O1 = __builtin_amdgcn_mfma_f32_32x32x16_bf16(v1, pa[c], O1, 0, 0, 0);
    }
    __builtin_amdgcn_s_setprio(0);
  };

  // main causal loop: double-buffered, ONE barrier per step
  stage_load(0);
  stage_write(0);
  for (int kb = 0; kb < nkv_b; ++kb) {
    if (kb + 1 < nkv_b) stage_load(kb + 1);
    __syncthreads();
    if (kb < nkv_w) compute(kb, kb & 1);
    if (kb + 1 < nkv_b) stage_write((kb + 1) & 1);
  }

  // pathological rows (entire visible prefix padded): extend over all keys
  if (tid == 0) flagv = 0;
  __syncthreads();
  if (m_run <= -7.2e8f) flagv = 1;
  __syncthreads();
  if (flagv) {
    for (int kb = nkv_b - 1; kb < 32; ++kb) {
      if (kb + 1 < 32) stage_load(kb + 1);
      __syncthreads();
      if (kb >= nkv_w) compute(kb, kb & 1);
      if (kb + 1 < 32) stage_write((kb + 1) & 1);
    }
  }

  // epilogue: O0[r] = O[d=(r&3)+8*(r>>2)+4*hi][q=qw+ln31]; lane owns row q.
  {
    const float inv = 1.0f / l_run;
    unsigned short* op = ao + (size_t)(b * 2048 + qw + ln31) * 1024 + h * 64;
#pragma unroll
    for (int g2 = 0; g2 < 4; ++g2) {
      const int d0 = 8 * g2 + 4 * hi;
      *(ushort4*)(op + d0) = make_ushort4(
          f2b(O0[g2 * 4 + 0] * inv), f2b(O0[g2 * 4 + 1] * inv),
          f2b(O0[g2 * 4 + 2] * inv), f2b(O0[g2 * 4 + 3] * inv));
      *(ushort4*)(op + 32 + d0) = make_ushort4(
          f2b(O1[g2 * 4 + 0] * inv), f2b(O1[g2 * 4 + 1] * inv),
          f2b(O1[g2 * 4 + 2] * inv), f2b(O1[g2 * 4 + 3] * inv));
    }
  }
}

extern "C" void kernel_launch(void* const* d_in, const int* in_sizes, int n_in,
                              void* d_out, int out_size, void* d_ws, size_t ws_size,
                              hipStream_t stream) {
  const float* q  = (const float*)d_in[0];
  const float* k  = (const float*)d_in[1];
  const float* v  = (const float*)d_in[2];
  const void*  kpm = d_in[4];
  const float* Wq = (const float*)d_in[5];
  const float* Wk = (const float*)d_in[6];
  const float* Wv = (const float*)d_in[7];
  const float* Wo = (const float*)d_in[8];

  char* ws = (char*)d_ws;
  unsigned short* qh = (unsigned short*)(ws);                       // 8 MB (b,h,t,d)
  unsigned short* kh = (unsigned short*)(ws + (8u << 20));          // 8 MB
  unsigned short* vt = (unsigned short*)(ws + (16u << 20));         // 8 MB (b,h,d,t)
  unsigned short* ao = (unsigned short*)(ws + (24u << 20));         // 8 MB (B*T, D)
  unsigned short* Wb = (unsigned short*)(ws + (32u << 20));         // 8 MB (4 x 1M)
  float* sin_t = (float*)(ws + (40u << 20));                        // 512 KB
  float* cos_t = (float*)(ws + (40u << 20) + 524288);               // 512 KB
  unsigned long long* pmask = (unsigned long long*)(ws + (41u << 20));  // 512 B
  int* mflag = (int*)(ws + (41u << 20) + 512);
  unsigned short* qb = (unsigned short*)(ws + (42u << 20));         // 8 MB bf16 q
  unsigned short* kb = (unsigned short*)(ws + (50u << 20));         // 8 MB bf16 k
  unsigned short* vb = (unsigned short*)(ws + (58u << 20));         // 8 MB bf16 v

  const bool big = ws_size >= (66ull << 20);

  (void)hipMemsetAsync(mflag, 0, sizeof(int), stream);
  detect_mask_k<<<1, 256, 0, stream>>>((const unsigned int*)kpm, mflag);
  mask_pack_k<<<1, 256, 0, stream>>>(kpm, mflag, pmask);
  rope_table_k<<<512, 256, 0, stream>>>(sin_t, cos_t);
  convw_k<<<2048, 256, 0, stream>>>(Wq, Wk, Wv, Wo, Wb);

  dim3 gq(32, 8, 3);
  if (big) {
    conv_in_k<<<6144, 256, 0, stream>>>(q, k, v, qb, kb, vb);
    qkv_k<true><<<gq, 256, 0, stream>>>(qb, kb, vb, Wb, sin_t, cos_t, qh, kh, vt);
  } else {
    qkv_k<false><<<gq, 256, 0, stream>>>(q, k, v, Wb, sin_t, cos_t, qh, kh, vt);
  }

  attn_k<<<512, 256, 0, stream>>>(qh, kh, vt, pmask, ao);

  gemm_o_k<<<dim3(64, 8), 256, 0, stream>>>(ao, Wb + 3145728, (float*)d_out);
}

// Round 15
// 129.657 us; speedup vs baseline: 1.2010x; 1.1308x over previous
//
#include <hip/hip_runtime.h>
#include <stdint.h>

typedef __bf16 bf16x8 __attribute__((ext_vector_type(8)));
typedef float f32x4 __attribute__((ext_vector_type(4)));
typedef float f32x16 __attribute__((ext_vector_type(16)));

#define NEG_BIG2 (-1.442695040e9f)      // -1e9 * log2(e)
#define SC_LOG2  (0.180336880f)         // 0.125 * log2(e)

__device__ __forceinline__ unsigned short f2b(float f) {
  union { float f; unsigned int u; } c; c.f = f;
  unsigned int u = c.u;
  u += 0x7FFFu + ((u >> 16) & 1u);
  return (unsigned short)(u >> 16);
}
__device__ __forceinline__ float b2f(unsigned short h) {
  union { unsigned int u; float f; } c; c.u = ((unsigned int)h) << 16;
  return c.f;
}
__device__ __forceinline__ unsigned int pk2(float a, float b) {
  __bf16 x = (__bf16)a, y = (__bf16)b;
  unsigned short xu, yu;
  __builtin_memcpy(&xu, &x, 2);
  __builtin_memcpy(&yu, &y, 2);
  return (unsigned)xu | ((unsigned)yu << 16);
}
// raw v_exp_f32: D = 2^x
__device__ __forceinline__ float ex2(float x) {
  float r; asm("v_exp_f32 %0, %1" : "=v"(r) : "v"(x)); return r;
}

// global -> LDS direct (16B per lane)
typedef const __attribute__((address_space(1))) unsigned int ga_u32;
typedef __attribute__((address_space(3))) unsigned int ls_u32;
__device__ __forceinline__ void gld16(const void* g, void* l) {
  __builtin_amdgcn_global_load_lds((ga_u32*)g, (ls_u32*)l, 16, 0, 0);
}

__device__ __forceinline__ void swap_pair(unsigned a, unsigned b, int hi,
                                          unsigned& lo_out, unsigned& hi_out) {
#if __has_builtin(__builtin_amdgcn_permlane32_swap)
  auto r = __builtin_amdgcn_permlane32_swap(a, b, false, false);
  lo_out = r[0]; hi_out = r[1];
#else
  unsigned pa = __shfl_xor(a, 32), pb = __shfl_xor(b, 32);
  lo_out = hi ? pb : a;
  hi_out = hi ? b : pa;
#endif
}

// ---------------- fused prologue: mask detect+pack / rope table / W conv /
// ---------------- q,k,v conv.  One dispatch, branch on blockIdx ranges. ------
__global__ __launch_bounds__(256) void prep_k(
    const void* __restrict__ kpm,
    const float* __restrict__ Wq, const float* __restrict__ Wk,
    const float* __restrict__ Wv, const float* __restrict__ Wo,
    const float* __restrict__ q, const float* __restrict__ k,
    const float* __restrict__ v,
    unsigned long long* __restrict__ pmask,
    float* __restrict__ sin_t, float* __restrict__ cos_t,
    unsigned short* __restrict__ Wb,
    unsigned short* __restrict__ qb, unsigned short* __restrict__ kb,
    unsigned short* __restrict__ vb) {
  const int bid = blockIdx.x, tid = threadIdx.x;
  if (bid == 0) {
    // mask dtype detect (LDS flag) + pack into per-(b, kv64) 64-bit masks
    __shared__ int flg;
    if (tid == 0) flg = 0;
    __syncthreads();
    unsigned int vv = 0;
    for (int i = tid; i < 1024; i += 256) vv |= ((const unsigned int*)kpm)[i];
    if (vv & ~1u) atomicOr(&flg, 1);
    __syncthreads();
    const int bytes = flg;
    const int w = tid >> 6, lane = tid & 63;
    for (int i = w; i < 64; i += 4) {
      int b = i >> 5, kbq = i & 31;
      int idx = b * 2048 + kbq * 64 + lane;
      int pad = bytes ? (int)((const unsigned char*)kpm)[idx] : ((const int*)kpm)[idx];
      unsigned long long pm = __ballot(pad != 0);
      if (lane == 0) pmask[i] = pm;
    }
  } else if (bid < 513) {
    // RoPE sin/cos table
    int i = (bid - 1) * 256 + tid;  // 2048*64
    int t = i >> 6, d = i & 63, f = d & 31;
    double inv = exp(-((double)(2 * f) / 64.0) * log(10000.0));
    double ang = (double)t * inv;
    sin_t[i] = (float)sin(ang);
    cos_t[i] = (float)cos(ang);
  } else if (bid < 2561) {
    // weight fp32 -> bf16
    size_t g = (size_t)(bid - 513) * 256 + tid;
    size_t i8 = g * 8;
    int t = (int)(i8 >> 20);
    const float* src = (t == 0 ? Wq : t == 1 ? Wk : t == 2 ? Wv : Wo) + (i8 & 1048575);
    float4 a = *(const float4*)src, c = *(const float4*)(src + 4);
    uint4 o = { pk2(a.x, a.y), pk2(a.z, a.w), pk2(c.x, c.y), pk2(c.z, c.w) };
    *(uint4*)&Wb[i8] = o;
  } else {
    // q,k,v fp32 -> bf16
    size_t g = (size_t)(bid - 2561) * 256 + tid;
    size_t i8 = g * 8;
    int t = (int)(i8 >> 22);
    size_t off = i8 & 4194303;
    const float* src = (t == 0 ? q : t == 1 ? k : v) + off;
    unsigned short* dst = (t == 0 ? qb : t == 1 ? kb : vb) + off;
    float4 a = *(const float4*)src, c = *(const float4*)(src + 4);
    uint4 o = { pk2(a.x, a.y), pk2(a.z, a.w), pk2(c.x, c.y), pk2(c.z, c.w) };
    *(uint4*)dst = o;
  }
}

// ---------------- fused QKV projection GEMM (grid.z selects q/k/v) ------------
// z=0 -> qh (b,h,t,d), RoPE fused + pre-scaled by 0.125*log2(e)
// z=1 -> kh (b,h,t,d), RoPE fused
// z=2 -> vt (b,h,d,t)
template<bool ABF>
__global__ __launch_bounds__(256) void qkv_k(const void* __restrict__ A0,
                                             const void* __restrict__ A1,
                                             const void* __restrict__ A2,
                                             const unsigned short* __restrict__ Wb,
                                             const float* __restrict__ sin_t,
                                             const float* __restrict__ cos_t,
                                             unsigned short* __restrict__ qh,
                                             unsigned short* __restrict__ kh,
                                             unsigned short* __restrict__ vt) {
  const int z = blockIdx.z;
  const void* Ap = (z == 0) ? A0 : (z == 1) ? A1 : A2;
  const unsigned short* Wp = Wb + (size_t)z * 1048576;
  unsigned short* outp = (z == 0) ? qh : (z == 1) ? kh : vt;

  __shared__ unsigned short As[2][128 * 32];
  __shared__ unsigned short Bs[2][128 * 32];
  const int M0 = blockIdx.x * 128, N0 = blockIdx.y * 128;
  const int tid = threadIdx.x, lane = tid & 63, w = tid >> 6;
  const int wr = w >> 1, wc = w & 1;
  const int lrow = lane & 15, lgrp = lane >> 4;

  const f32x4 Z4 = {0.f, 0.f, 0.f, 0.f};
  f32x4 acc[4][4];
#pragma unroll
  for (int i = 0; i < 4; ++i)
#pragma unroll
    for (int j = 0; j < 4; ++j) acc[i][j] = Z4;

  auto STAGE = [&](int bu, int kt) {
    if (ABF) {
      const unsigned short* Ab = (const unsigned short*)Ap;
#pragma unroll
      for (int i = 0; i < 2; ++i) {
        const unsigned short* gA = Ab +
            (size_t)(M0 + i * 64 + w * 16 + (lane >> 2)) * 1024 + kt + (lane & 3) * 8;
        gld16(gA, &As[bu][i * 2048 + w * 512]);
      }
    } else {
      const int row = tid >> 1, half = tid & 1;
      const float* ap = (const float*)Ap + (size_t)(M0 + row) * 1024 + kt + half * 16;
      float4 f0 = *(const float4*)ap, f1 = *(const float4*)(ap + 4);
      float4 f2 = *(const float4*)(ap + 8), f3 = *(const float4*)(ap + 12);
      uint4 u0 = { pk2(f0.x, f0.y), pk2(f0.z, f0.w), pk2(f1.x, f1.y), pk2(f1.z, f1.w) };
      uint4 u1 = { pk2(f2.x, f2.y), pk2(f2.z, f2.w), pk2(f3.x, f3.y), pk2(f3.z, f3.w) };
      *(uint4*)&As[bu][row * 32 + half * 16] = u0;
      *(uint4*)&As[bu][row * 32 + half * 16 + 8] = u1;
    }
#pragma unroll
    for (int i = 0; i < 2; ++i) {
      const unsigned short* gB = Wp +
          (size_t)(N0 + i * 64 + w * 16 + (lane >> 2)) * 1024 + kt + (lane & 3) * 8;
      gld16(gB, &Bs[bu][i * 2048 + w * 512]);
    }
  };

  STAGE(0, 0);
  int cur = 0;
  for (int kt = 0; kt < 1024; kt += 32) {
    __syncthreads();
    if (kt + 32 < 1024) STAGE(cur ^ 1, kt + 32);
    bf16x8 af[4], bfv[4];
#pragma unroll
    for (int m = 0; m < 4; ++m)
      af[m] = *(const bf16x8*)&As[cur][(wr * 64 + m * 16 + lrow) * 32 + lgrp * 8];
#pragma unroll
    for (int n = 0; n < 4; ++n)
      bfv[n] = *(const bf16x8*)&Bs[cur][(wc * 64 + n * 16 + lrow) * 32 + lgrp * 8];
    __builtin_amdgcn_s_setprio(1);
#pragma unroll
    for (int m = 0; m < 4; ++m)
#pragma unroll
      for (int n = 0; n < 4; ++n)
        acc[m][n] = __builtin_amdgcn_mfma_f32_16x16x32_bf16(af[m], bfv[n], acc[m][n], 0, 0, 0);
    __builtin_amdgcn_s_setprio(0);
    cur ^= 1;
  }

#pragma unroll
  for (int mi = 0; mi < 4; ++mi)
#pragma unroll
    for (int ni = 0; ni < 4; ++ni) {
      const int m = M0 + wr * 64 + mi * 16 + lgrp * 4;  // + r
      const int n = N0 + wc * 64 + ni * 16 + lrow;
      const int b = m >> 11, t = m & 2047;
      const int d = n & 63;
      if (z < 2) {
        const float sc = (z == 0) ? SC_LOG2 : 1.0f;   // Q pre-scaled to log2 dom
        unsigned short* o = outp +
            ((size_t)(b * 16 + (n >> 6)) * 2048 + t) * 64 + d;
#pragma unroll
        for (int r = 0; r < 4; ++r) {
          const float xv = acc[mi][ni][r];
          const float pr = __shfl_xor(xv, 1);         // x[d^1], same row
          const int tt = t + r;
          const float cs = cos_t[tt * 64 + d];
          const float sn = sin_t[tt * 64 + d];
          const float ov = (xv * cs + ((d & 1) ? pr : -pr) * sn) * sc;
          o[(size_t)r * 64] = f2b(ov);
        }
      } else {
        unsigned short* o = outp +
            ((size_t)(b * 16 + (n >> 6)) * 64 + d) * 2048 + t;
        *(ushort4*)o = make_ushort4(f2b(acc[mi][ni][0]), f2b(acc[mi][ni][1]),
                                    f2b(acc[mi][ni][2]), f2b(acc[mi][ni][3]));
      }
    }
}

// ---------------- output projection GEMM: BM=64, dbuf, 1 barrier/K-step -------
__global__ __launch_bounds__(256) void gemm_o_k(const unsigned short* __restrict__ Ab,
                                                const unsigned short* __restrict__ Wp,
                                                float* __restrict__ outp) {
  __shared__ unsigned short As[2][64 * 32];
  __shared__ unsigned short Bs[2][128 * 32];
  const int M0 = blockIdx.x * 64, N0 = blockIdx.y * 128;
  const int tid = threadIdx.x, lane = tid & 63, w = tid >> 6;
  const int wr = w >> 1, wc = w & 1;
  const int lrow = lane & 15, lgrp = lane >> 4;

  const f32x4 Z4 = {0.f, 0.f, 0.f, 0.f};
  f32x4 acc[2][4];
#pragma unroll
  for (int i = 0; i < 2; ++i)
#pragma unroll
    for (int j = 0; j < 4; ++j) acc[i][j] = Z4;

  auto STAGE = [&](int bu, int kt) {
    {
      const unsigned short* gA = Ab +
          (size_t)(M0 + w * 16 + (lane >> 2)) * 1024 + kt + (lane & 3) * 8;
      gld16(gA, &As[bu][w * 512]);
    }
#pragma unroll
    for (int i = 0; i < 2; ++i) {
      const unsigned short* gB = Wp +
          (size_t)(N0 + i * 64 + w * 16 + (lane >> 2)) * 1024 + kt + (lane & 3) * 8;
      gld16(gB, &Bs[bu][i * 2048 + w * 512]);
    }
  };

  STAGE(0, 0);
  int cur = 0;
  for (int kt = 0; kt < 1024; kt += 32) {
    __syncthreads();
    if (kt + 32 < 1024) STAGE(cur ^ 1, kt + 32);
    bf16x8 af[2], bfv[4];
#pragma unroll
    for (int m = 0; m < 2; ++m)
      af[m] = *(const bf16x8*)&As[cur][(wr * 32 + m * 16 + lrow) * 32 + lgrp * 8];
#pragma unroll
    for (int n = 0; n < 4; ++n)
      bfv[n] = *(const bf16x8*)&Bs[cur][(wc * 64 + n * 16 + lrow) * 32 + lgrp * 8];
    __builtin_amdgcn_s_setprio(1);
#pragma unroll
    for (int m = 0; m < 2; ++m)
#pragma unroll
      for (int n = 0; n < 4; ++n)
        acc[m][n] = __builtin_amdgcn_mfma_f32_16x16x32_bf16(af[m], bfv[n], acc[m][n], 0, 0, 0);
    __builtin_amdgcn_s_setprio(0);
    cur ^= 1;
  }

#pragma unroll
  for (int mi = 0; mi < 2; ++mi)
#pragma unroll
    for (int ni = 0; ni < 4; ++ni) {
      const int m = M0 + wr * 32 + mi * 16 + lgrp * 4;  // + r
      const int n = N0 + wc * 64 + ni * 16 + lrow;
      float* o = outp + (size_t)m * 1024 + n;
#pragma unroll
      for (int r = 0; r < 4; ++r) o[(size_t)r * 1024] = acc[mi][ni][r];
    }
}

// ---------------- Flash attention (round-12 structure; Q pre-scaled) ----------
// S^T = mfma(K, Q): q on C/D COLUMN (lane&31); scores arrive already in log2
// domain (Q carries 0.125*log2e).  Defer-max online softmax.  O^T = mfma(V,P).
// Double-buffered, ONE barrier per KV step.
__global__ __launch_bounds__(256, 2) void attn_k(
    const unsigned short* __restrict__ qh, const unsigned short* __restrict__ kh,
    const unsigned short* __restrict__ vt, const unsigned long long* __restrict__ pmask,
    unsigned short* __restrict__ ao) {
  // work-descending + XCD-grouped decode: 512 blocks
  const int bid = blockIdx.x;
  const int x = bid & 7, g = bid >> 3;
  const int bh = x * 4 + (g & 3);
  const int tile = 15 - (g >> 2);
  const int b = bh >> 4, h = bh & 15;
  const int tid = threadIdx.x, lane = tid & 63, w = tid >> 6;
  const int ln31 = lane & 31, hi = lane >> 5;

  __shared__ char Kb[2][8192];
  __shared__ char Vb[2][8192];
  __shared__ int flagv;

  const size_t bh_off = (size_t)bh * 2048 * 64;
  const int qw = tile * 128 + w * 32;
  const int q_abs = qw + ln31;
  const int nkv_w = qw / 64 + 1;
  const int nkv_b = tile * 2 + 2;
  const int swz = (ln31 & 7) << 4;

  bf16x8 qf[4];
#pragma unroll
  for (int dc = 0; dc < 4; ++dc)
    qf[dc] = *(const bf16x8*)(qh + bh_off + (size_t)(qw + ln31) * 64 + dc * 16 + hi * 8);

  const f32x16 Z16 = {0.f,0.f,0.f,0.f,0.f,0.f,0.f,0.f,0.f,0.f,0.f,0.f,0.f,0.f,0.f,0.f};
  f32x16 O0 = Z16, O1 = Z16;
  float m_run = -INFINITY, l_run = 0.f;

  uint4 kr0, kr1, vr0, vr1;
  const int srow = tid >> 2, sseg = tid & 3;
  const int sbase = srow * 128 + sseg * 32;
  const int sswz = (srow & 7) << 4;

  auto stage_load = [&](int kbi) {
    const unsigned short* kp = kh + bh_off + (size_t)(kbi * 64 + srow) * 64 + sseg * 16;
    kr0 = *(const uint4*)kp; kr1 = *(const uint4*)(kp + 8);
    const unsigned short* vp = vt + bh_off + (size_t)srow * 2048 + kbi * 64 + sseg * 16;
    vr0 = *(const uint4*)vp; vr1 = *(const uint4*)(vp + 8);
  };
  auto stage_write = [&](int bu) {
    *(uint4*)(Kb[bu] + (sbase ^ sswz)) = kr0;
    *(uint4*)(Kb[bu] + ((sbase + 16) ^ sswz)) = kr1;
    *(uint4*)(Vb[bu] + (sbase ^ sswz)) = vr0;
    *(uint4*)(Vb[bu] + ((sbase + 16) ^ sswz)) = vr1;
  };

  auto compute = [&](int kb, int cur) {
    const unsigned long long pmh = pmask[b * 32 + kb] >> (hi * 4);
    f32x16 S0 = Z16, S1 = Z16;
    __builtin_amdgcn_s_setprio(1);
#pragma unroll
    for (int dc = 0; dc < 4; ++dc) {
      bf16x8 k0 = *(const bf16x8*)(Kb[cur] + ((ln31 * 128 + dc * 32 + hi * 16) ^ swz));
      bf16x8 k1 = *(const bf16x8*)(Kb[cur] + (((ln31 + 32) * 128 + dc * 32 + hi * 16) ^ swz));
      S0 = __builtin_amdgcn_mfma_f32_32x32x16_bf16(k0, qf[dc], S0, 0, 0, 0);
      S1 = __builtin_amdgcn_mfma_f32_32x32x16_bf16(k1, qf[dc], S1, 0, 0, 0);
    }
    __builtin_amdgcn_s_setprio(0);

    // scores already log2-domain (Q pre-scaled); mask only
    const bool diag = (kb * 64 + 63) > qw;
    if (diag) {
#pragma unroll
      for (int r = 0; r < 16; ++r) {
        const int kloc = (r & 3) + 8 * (r >> 2);
        float sv = S0[r];
        sv = ((pmh >> kloc) & 1) ? NEG_BIG2
             : ((kb * 64 + kloc + 4 * hi > q_abs) ? sv + NEG_BIG2 : sv);
        S0[r] = sv;
        float sw = S1[r];
        sw = ((pmh >> (kloc + 32)) & 1) ? NEG_BIG2
             : ((kb * 64 + 32 + kloc + 4 * hi > q_abs) ? sw + NEG_BIG2 : sw);
        S1[r] = sw;
      }
    } else {
#pragma unroll
      for (int r = 0; r < 16; ++r) {
        const int kloc = (r & 3) + 8 * (r >> 2);
        S0[r] = ((pmh >> kloc) & 1) ? NEG_BIG2 : S0[r];
        S1[r] = ((pmh >> (kloc + 32)) & 1) ? NEG_BIG2 : S1[r];
      }
    }

    float vm = fmaxf(S0[0], S0[1]);
#pragma unroll
    for (int r = 2; r < 16; r += 2) vm = fmaxf(vm, fmaxf(S0[r], S0[r + 1]));
#pragma unroll
    for (int r = 0; r < 16; r += 2) vm = fmaxf(vm, fmaxf(S1[r], S1[r + 1]));
    vm = fmaxf(vm, __shfl_xor(vm, 32));

    if (__any(vm > m_run + 11.5f)) {
      const float mnew = fmaxf(m_run, vm);
      const float alpha = ex2(m_run - mnew);
      m_run = mnew;
      l_run *= alpha;
      O0 *= alpha; O1 *= alpha;
    }
    float rs = 0.f;
#pragma unroll
    for (int r = 0; r < 16; ++r) { float p = ex2(S0[r] - m_run); S0[r] = p; rs += p; }
#pragma unroll
    for (int r = 0; r < 16; ++r) { float p = ex2(S1[r] - m_run); S1[r] = p; rs += p; }
    rs += __shfl_xor(rs, 32);
    l_run += rs;

    union U8 { uint4 u; bf16x8 v; };
    bf16x8 pa[4];
#pragma unroll
    for (int kt = 0; kt < 2; ++kt) {
#pragma unroll
      for (int hf = 0; hf < 2; ++hf) {
        float p0, p1, p2, p3, p4, p5, p6, p7;
        if (kt == 0) {
          if (hf == 0) { p0=S0[0];p1=S0[1];p2=S0[2];p3=S0[3];p4=S0[4];p5=S0[5];p6=S0[6];p7=S0[7]; }
          else         { p0=S0[8];p1=S0[9];p2=S0[10];p3=S0[11];p4=S0[12];p5=S0[13];p6=S0[14];p7=S0[15]; }
        } else {
          if (hf == 0) { p0=S1[0];p1=S1[1];p2=S1[2];p3=S1[3];p4=S1[4];p5=S1[5];p6=S1[6];p7=S1[7]; }
          else         { p0=S1[8];p1=S1[9];p2=S1[10];p3=S1[11];p4=S1[12];p5=S1[13];p6=S1[14];p7=S1[15]; }
        }
        unsigned e0 = pk2(p0, p1), e1 = pk2(p2, p3);
        unsigned o0 = pk2(p4, p5), o1 = pk2(p6, p7);
        unsigned a0, b0_, a1, b1_;
        swap_pair(e0, o0, hi, a0, b0_);
        swap_pair(e1, o1, hi, a1, b1_);
        U8 u; u.u = make_uint4(a0, a1, b0_, b1_);
        pa[kt * 2 + hf] = u.v;
      }
    }

    __builtin_amdgcn_s_setprio(1);
#pragma unroll
    for (int c = 0; c < 4; ++c) {
      bf16x8 v0 = *(const bf16x8*)(Vb[cur] + ((ln31 * 128 + c * 32 + hi * 16) ^ swz));
      bf16x8 v1 = *(const bf16x8*)(Vb[cur] + (((ln31 + 32) * 128 + c * 32 + hi * 16) ^ swz));
      O0 = __builtin_amdgcn_mfma_f32_32x32x16_bf16(v0, pa[c], O0, 0, 0, 0);
      O1 = __builtin_amdgcn_mfma_f32_32x32x16_bf16(v1, pa[c], O1, 0, 0, 0);
    }
    __builtin_amdgcn_s_setprio(0);
  };

  // main causal loop: double-buffered, ONE barrier per step
  stage_load(0);
  stage_write(0);
  for (int kb = 0; kb < nkv_b; ++kb) {
    if (kb + 1 < nkv_b) stage_load(kb + 1);
    __syncthreads();
    if (kb < nkv_w) compute(kb, kb & 1);
    if (kb + 1 < nkv_b) stage_write((kb + 1) & 1);
  }

  // pathological rows (entire visible prefix padded): extend over all keys
  if (tid == 0) flagv = 0;
  __syncthreads();
  if (m_run <= -7.2e8f) flagv = 1;
  __syncthreads();
  if (flagv) {
    for (int kb = nkv_b - 1; kb < 32; ++kb) {
      if (kb + 1 < 32) stage_load(kb + 1);
      __syncthreads();
      if (kb >= nkv_w) compute(kb, kb & 1);
      if (kb + 1 < 32) stage_write((kb + 1) & 1);
    }
  }

  // epilogue: O0[r] = O[d=(r&3)+8*(r>>2)+4*hi][q=qw+ln31]; lane owns row q.
  {
    const float inv = 1.0f / l_run;
    unsigned short* op = ao + (size_t)(b * 2048 + qw + ln31) * 1024 + h * 64;
#pragma unroll
    for (int g2 = 0; g2 < 4; ++g2) {
      const int d0 = 8 * g2 + 4 * hi;
      *(ushort4*)(op + d0) = make_ushort4(
          f2b(O0[g2 * 4 + 0] * inv), f2b(O0[g2 * 4 + 1] * inv),
          f2b(O0[g2 * 4 + 2] * inv), f2b(O0[g2 * 4 + 3] * inv));
      *(ushort4*)(op + 32 + d0) = make_ushort4(
          f2b(O1[g2 * 4 + 0] * inv), f2b(O1[g2 * 4 + 1] * inv),
          f2b(O1[g2 * 4 + 2] * inv), f2b(O1[g2 * 4 + 3] * inv));
    }
  }
}

extern "C" void kernel_launch(void* const* d_in, const int* in_sizes, int n_in,
                              void* d_out, int out_size, void* d_ws, size_t ws_size,
                              hipStream_t stream) {
  const float* q  = (const float*)d_in[0];
  const float* k  = (const float*)d_in[1];
  const float* v  = (const float*)d_in[2];
  const void*  kpm = d_in[4];
  const float* Wq = (const float*)d_in[5];
  const float* Wk = (const float*)d_in[6];
  const float* Wv = (const float*)d_in[7];
  const float* Wo = (const float*)d_in[8];

  char* ws = (char*)d_ws;
  unsigned short* qh = (unsigned short*)(ws);                       // 8 MB (b,h,t,d)
  unsigned short* kh = (unsigned short*)(ws + (8u << 20));          // 8 MB
  unsigned short* vt = (unsigned short*)(ws + (16u << 20));         // 8 MB (b,h,d,t)
  unsigned short* ao = (unsigned short*)(ws + (24u << 20));         // 8 MB (B*T, D)
  unsigned short* Wb = (unsigned short*)(ws + (32u << 20));         // 8 MB (4 x 1M)
  float* sin_t = (float*)(ws + (40u << 20));                        // 512 KB
  float* cos_t = (float*)(ws + (40u << 20) + 524288);               // 512 KB
  unsigned long long* pmask = (unsigned long long*)(ws + (41u << 20));  // 512 B
  unsigned short* qb = (unsigned short*)(ws + (42u << 20));         // 8 MB bf16 q
  unsigned short* kb = (unsigned short*)(ws + (50u << 20));         // 8 MB bf16 k
  unsigned short* vb = (unsigned short*)(ws + (58u << 20));         // 8 MB bf16 v

  const bool big = ws_size >= (66ull << 20);

  // fused prologue: block 0 = mask, 1..512 = rope table, 513..2560 = W conv,
  // 2561..8704 = q/k/v conv (only when big).
  prep_k<<<big ? 8705 : 2561, 256, 0, stream>>>(
      kpm, Wq, Wk, Wv, Wo, q, k, v, pmask, sin_t, cos_t, Wb, qb, kb, vb);

  dim3 gq(32, 8, 3);
  if (big) {
    qkv_k<true><<<gq, 256, 0, stream>>>(qb, kb, vb, Wb, sin_t, cos_t, qh, kh, vt);
  } else {
    qkv_k<false><<<gq, 256, 0, stream>>>(q, k, v, Wb, sin_t, cos_t, qh, kh, vt);
  }

  attn_k<<<512, 256, 0, stream>>>(qh, kh, vt, pmask, ao);

  gemm_o_k<<<dim3(64, 8), 256, 0, stream>>>(ao, Wb + 3145728, (float*)d_out);
}

// Round 16
// 129.436 us; speedup vs baseline: 1.2030x; 1.0017x over previous
//
#include <hip/hip_runtime.h>
#include <stdint.h>

typedef __bf16 bf16x8 __attribute__((ext_vector_type(8)));
typedef float f32x4 __attribute__((ext_vector_type(4)));
typedef float f32x16 __attribute__((ext_vector_type(16)));

#define NEG_BIG2 (-1.442695040e9f)      // -1e9 * log2(e)
#define SC_LOG2  (0.180336880f)         // 0.125 * log2(e)

__device__ __forceinline__ unsigned short f2b(float f) {
  union { float f; unsigned int u; } c; c.f = f;
  unsigned int u = c.u;
  u += 0x7FFFu + ((u >> 16) & 1u);
  return (unsigned short)(u >> 16);
}
__device__ __forceinline__ float b2f(unsigned short h) {
  union { unsigned int u; float f; } c; c.u = ((unsigned int)h) << 16;
  return c.f;
}
__device__ __forceinline__ unsigned int pk2(float a, float b) {
  __bf16 x = (__bf16)a, y = (__bf16)b;
  unsigned short xu, yu;
  __builtin_memcpy(&xu, &x, 2);
  __builtin_memcpy(&yu, &y, 2);
  return (unsigned)xu | ((unsigned)yu << 16);
}
// raw v_exp_f32: D = 2^x
__device__ __forceinline__ float ex2(float x) {
  float r; asm("v_exp_f32 %0, %1" : "=v"(r) : "v"(x)); return r;
}

// global -> LDS direct (16B per lane)
typedef const __attribute__((address_space(1))) unsigned int ga_u32;
typedef __attribute__((address_space(3))) unsigned int ls_u32;
__device__ __forceinline__ void gld16(const void* g, void* l) {
  __builtin_amdgcn_global_load_lds((ga_u32*)g, (ls_u32*)l, 16, 0, 0);
}

__device__ __forceinline__ void swap_pair(unsigned a, unsigned b, int hi,
                                          unsigned& lo_out, unsigned& hi_out) {
#if __has_builtin(__builtin_amdgcn_permlane32_swap)
  auto r = __builtin_amdgcn_permlane32_swap(a, b, false, false);
  lo_out = r[0]; hi_out = r[1];
#else
  unsigned pa = __shfl_xor(a, 32), pb = __shfl_xor(b, 32);
  lo_out = hi ? pb : a;
  hi_out = hi ? b : pa;
#endif
}

// ---------------- fused prologue: mask detect+pack / rope table / W conv /
// ---------------- q,k,v conv.  One dispatch, branch on blockIdx ranges. ------
__global__ __launch_bounds__(256) void prep_k(
    const void* __restrict__ kpm,
    const float* __restrict__ Wq, const float* __restrict__ Wk,
    const float* __restrict__ Wv, const float* __restrict__ Wo,
    const float* __restrict__ q, const float* __restrict__ k,
    const float* __restrict__ v,
    unsigned long long* __restrict__ pmask,
    float* __restrict__ sin_t, float* __restrict__ cos_t,
    unsigned short* __restrict__ Wb,
    unsigned short* __restrict__ qb, unsigned short* __restrict__ kb,
    unsigned short* __restrict__ vb) {
  const int bid = blockIdx.x, tid = threadIdx.x;
  if (bid == 0) {
    __shared__ int flg;
    if (tid == 0) flg = 0;
    __syncthreads();
    unsigned int vv = 0;
    for (int i = tid; i < 1024; i += 256) vv |= ((const unsigned int*)kpm)[i];
    if (vv & ~1u) atomicOr(&flg, 1);
    __syncthreads();
    const int bytes = flg;
    const int w = tid >> 6, lane = tid & 63;
    for (int i = w; i < 64; i += 4) {
      int b = i >> 5, kbq = i & 31;
      int idx = b * 2048 + kbq * 64 + lane;
      int pad = bytes ? (int)((const unsigned char*)kpm)[idx] : ((const int*)kpm)[idx];
      unsigned long long pm = __ballot(pad != 0);
      if (lane == 0) pmask[i] = pm;
    }
  } else if (bid < 513) {
    int i = (bid - 1) * 256 + tid;  // 2048*64
    int t = i >> 6, d = i & 63, f = d & 31;
    double inv = exp(-((double)(2 * f) / 64.0) * log(10000.0));
    double ang = (double)t * inv;
    sin_t[i] = (float)sin(ang);
    cos_t[i] = (float)cos(ang);
  } else if (bid < 2561) {
    size_t g = (size_t)(bid - 513) * 256 + tid;
    size_t i8 = g * 8;
    int t = (int)(i8 >> 20);
    const float* src = (t == 0 ? Wq : t == 1 ? Wk : t == 2 ? Wv : Wo) + (i8 & 1048575);
    float4 a = *(const float4*)src, c = *(const float4*)(src + 4);
    uint4 o = { pk2(a.x, a.y), pk2(a.z, a.w), pk2(c.x, c.y), pk2(c.z, c.w) };
    *(uint4*)&Wb[i8] = o;
  } else {
    size_t g = (size_t)(bid - 2561) * 256 + tid;
    size_t i8 = g * 8;
    int t = (int)(i8 >> 22);
    size_t off = i8 & 4194303;
    const float* src = (t == 0 ? q : t == 1 ? k : v) + off;
    unsigned short* dst = (t == 0 ? qb : t == 1 ? kb : vb) + off;
    float4 a = *(const float4*)src, c = *(const float4*)(src + 4);
    uint4 o = { pk2(a.x, a.y), pk2(a.z, a.w), pk2(c.x, c.y), pk2(c.z, c.w) };
    *(uint4*)dst = o;
  }
}

// ---------------- fused QKV projection GEMM (grid.z selects q/k/v) ------------
// z=0 -> qh (b,h,t,d), RoPE fused + pre-scaled by 0.125*log2(e)
// z=1 -> kh (b,h,t,d), RoPE fused
// z=2 -> vt (b,h,d,t)
template<bool ABF>
__global__ __launch_bounds__(256) void qkv_k(const void* __restrict__ A0,
                                             const void* __restrict__ A1,
                                             const void* __restrict__ A2,
                                             const unsigned short* __restrict__ Wb,
                                             const float* __restrict__ sin_t,
                                             const float* __restrict__ cos_t,
                                             unsigned short* __restrict__ qh,
                                             unsigned short* __restrict__ kh,
                                             unsigned short* __restrict__ vt) {
  const int z = blockIdx.z;
  const void* Ap = (z == 0) ? A0 : (z == 1) ? A1 : A2;
  const unsigned short* Wp = Wb + (size_t)z * 1048576;
  unsigned short* outp = (z == 0) ? qh : (z == 1) ? kh : vt;

  __shared__ unsigned short As[2][128 * 32];
  __shared__ unsigned short Bs[2][128 * 32];
  const int M0 = blockIdx.x * 128, N0 = blockIdx.y * 128;
  const int tid = threadIdx.x, lane = tid & 63, w = tid >> 6;
  const int wr = w >> 1, wc = w & 1;
  const int lrow = lane & 15, lgrp = lane >> 4;

  const f32x4 Z4 = {0.f, 0.f, 0.f, 0.f};
  f32x4 acc[4][4];
#pragma unroll
  for (int i = 0; i < 4; ++i)
#pragma unroll
    for (int j = 0; j < 4; ++j) acc[i][j] = Z4;

  auto STAGE = [&](int bu, int kt) {
    if (ABF) {
      const unsigned short* Ab = (const unsigned short*)Ap;
#pragma unroll
      for (int i = 0; i < 2; ++i) {
        const unsigned short* gA = Ab +
            (size_t)(M0 + i * 64 + w * 16 + (lane >> 2)) * 1024 + kt + (lane & 3) * 8;
        gld16(gA, &As[bu][i * 2048 + w * 512]);
      }
    } else {
      const int row = tid >> 1, half = tid & 1;
      const float* ap = (const float*)Ap + (size_t)(M0 + row) * 1024 + kt + half * 16;
      float4 f0 = *(const float4*)ap, f1 = *(const float4*)(ap + 4);
      float4 f2 = *(const float4*)(ap + 8), f3 = *(const float4*)(ap + 12);
      uint4 u0 = { pk2(f0.x, f0.y), pk2(f0.z, f0.w), pk2(f1.x, f1.y), pk2(f1.z, f1.w) };
      uint4 u1 = { pk2(f2.x, f2.y), pk2(f2.z, f2.w), pk2(f3.x, f3.y), pk2(f3.z, f3.w) };
      *(uint4*)&As[bu][row * 32 + half * 16] = u0;
      *(uint4*)&As[bu][row * 32 + half * 16 + 8] = u1;
    }
#pragma unroll
    for (int i = 0; i < 2; ++i) {
      const unsigned short* gB = Wp +
          (size_t)(N0 + i * 64 + w * 16 + (lane >> 2)) * 1024 + kt + (lane & 3) * 8;
      gld16(gB, &Bs[bu][i * 2048 + w * 512]);
    }
  };

  STAGE(0, 0);
  int cur = 0;
  for (int kt = 0; kt < 1024; kt += 32) {
    __syncthreads();
    if (kt + 32 < 1024) STAGE(cur ^ 1, kt + 32);
    bf16x8 af[4], bfv[4];
#pragma unroll
    for (int m = 0; m < 4; ++m)
      af[m] = *(const bf16x8*)&As[cur][(wr * 64 + m * 16 + lrow) * 32 + lgrp * 8];
#pragma unroll
    for (int n = 0; n < 4; ++n)
      bfv[n] = *(const bf16x8*)&Bs[cur][(wc * 64 + n * 16 + lrow) * 32 + lgrp * 8];
    __builtin_amdgcn_s_setprio(1);
#pragma unroll
    for (int m = 0; m < 4; ++m)
#pragma unroll
      for (int n = 0; n < 4; ++n)
        acc[m][n] = __builtin_amdgcn_mfma_f32_16x16x32_bf16(af[m], bfv[n], acc[m][n], 0, 0, 0);
    __builtin_amdgcn_s_setprio(0);
    cur ^= 1;
  }

#pragma unroll
  for (int mi = 0; mi < 4; ++mi)
#pragma unroll
    for (int ni = 0; ni < 4; ++ni) {
      const int m = M0 + wr * 64 + mi * 16 + lgrp * 4;  // + r
      const int n = N0 + wc * 64 + ni * 16 + lrow;
      const int b = m >> 11, t = m & 2047;
      const int d = n & 63;
      if (z < 2) {
        const float sc = (z == 0) ? SC_LOG2 : 1.0f;   // Q pre-scaled to log2 dom
        unsigned short* o = outp +
            ((size_t)(b * 16 + (n >> 6)) * 2048 + t) * 64 + d;
#pragma unroll
        for (int r = 0; r < 4; ++r) {
          const float xv = acc[mi][ni][r];
          const float pr = __shfl_xor(xv, 1);         // x[d^1], same row
          const int tt = t + r;
          const float cs = cos_t[tt * 64 + d];
          const float sn = sin_t[tt * 64 + d];
          const float ov = (xv * cs + ((d & 1) ? pr : -pr) * sn) * sc;
          o[(size_t)r * 64] = f2b(ov);
        }
      } else {
        unsigned short* o = outp +
            ((size_t)(b * 16 + (n >> 6)) * 64 + d) * 2048 + t;
        *(ushort4*)o = make_ushort4(f2b(acc[mi][ni][0]), f2b(acc[mi][ni][1]),
                                    f2b(acc[mi][ni][2]), f2b(acc[mi][ni][3]));
      }
    }
}

// ---------------- output projection GEMM: BM=64, dbuf, 1 barrier/K-step -------
__global__ __launch_bounds__(256) void gemm_o_k(const unsigned short* __restrict__ Ab,
                                                const unsigned short* __restrict__ Wp,
                                                float* __restrict__ outp) {
  __shared__ unsigned short As[2][64 * 32];
  __shared__ unsigned short Bs[2][128 * 32];
  const int M0 = blockIdx.x * 64, N0 = blockIdx.y * 128;
  const int tid = threadIdx.x, lane = tid & 63, w = tid >> 6;
  const int wr = w >> 1, wc = w & 1;
  const int lrow = lane & 15, lgrp = lane >> 4;

  const f32x4 Z4 = {0.f, 0.f, 0.f, 0.f};
  f32x4 acc[2][4];
#pragma unroll
  for (int i = 0; i < 2; ++i)
#pragma unroll
    for (int j = 0; j < 4; ++j) acc[i][j] = Z4;

  auto STAGE = [&](int bu, int kt) {
    {
      const unsigned short* gA = Ab +
          (size_t)(M0 + w * 16 + (lane >> 2)) * 1024 + kt + (lane & 3) * 8;
      gld16(gA, &As[bu][w * 512]);
    }
#pragma unroll
    for (int i = 0; i < 2; ++i) {
      const unsigned short* gB = Wp +
          (size_t)(N0 + i * 64 + w * 16 + (lane >> 2)) * 1024 + kt + (lane & 3) * 8;
      gld16(gB, &Bs[bu][i * 2048 + w * 512]);
    }
  };

  STAGE(0, 0);
  int cur = 0;
  for (int kt = 0; kt < 1024; kt += 32) {
    __syncthreads();
    if (kt + 32 < 1024) STAGE(cur ^ 1, kt + 32);
    bf16x8 af[2], bfv[4];
#pragma unroll
    for (int m = 0; m < 2; ++m)
      af[m] = *(const bf16x8*)&As[cur][(wr * 32 + m * 16 + lrow) * 32 + lgrp * 8];
#pragma unroll
    for (int n = 0; n < 4; ++n)
      bfv[n] = *(const bf16x8*)&Bs[cur][(wc * 64 + n * 16 + lrow) * 32 + lgrp * 8];
    __builtin_amdgcn_s_setprio(1);
#pragma unroll
    for (int m = 0; m < 2; ++m)
#pragma unroll
      for (int n = 0; n < 4; ++n)
        acc[m][n] = __builtin_amdgcn_mfma_f32_16x16x32_bf16(af[m], bfv[n], acc[m][n], 0, 0, 0);
    __builtin_amdgcn_s_setprio(0);
    cur ^= 1;
  }

#pragma unroll
  for (int mi = 0; mi < 2; ++mi)
#pragma unroll
    for (int ni = 0; ni < 4; ++ni) {
      const int m = M0 + wr * 32 + mi * 16 + lgrp * 4;  // + r
      const int n = N0 + wc * 64 + ni * 16 + lrow;
      float* o = outp + (size_t)m * 1024 + n;
#pragma unroll
      for (int r = 0; r < 4; ++r) o[(size_t)r * 1024] = acc[mi][ni][r];
    }
}

// ---------------- Flash attention (round-15 body; balanced-pair decode) -------
// S^T = mfma(K, Q): q on C/D COLUMN (lane&31); scores already log2-domain.
// Defer-max online softmax.  O^T = mfma(V, P).  Dbuf, ONE barrier per step.
// Decode: XCD x = bid&7 owns bh {4x..4x+3}.  Each CU's two blocks are
// (j, j+32) with tiles (15-(j>>2), (j>>2)-8+8... ) summing to 15 -> 34
// staging-steps per CU CONSTANT (was 20..48), same bh -> K/V L2 reuse.
__global__ __launch_bounds__(256, 2) void attn_k(
    const unsigned short* __restrict__ qh, const unsigned short* __restrict__ kh,
    const unsigned short* __restrict__ vt, const unsigned long long* __restrict__ pmask,
    unsigned short* __restrict__ ao) {
  const int bid = blockIdx.x;
  const int x = bid & 7, j = bid >> 3;   // j in [0,64)
  const int bh = x * 4 + (j & 3);
  const int jj = j >> 2;                 // [0,16)
  const int tile = (j < 32) ? (15 - jj) : (jj - 8);
  const int b = bh >> 4, h = bh & 15;
  const int tid = threadIdx.x, lane = tid & 63, w = tid >> 6;
  const int ln31 = lane & 31, hi = lane >> 5;

  __shared__ char Kb[2][8192];
  __shared__ char Vb[2][8192];
  __shared__ int flagv;

  const size_t bh_off = (size_t)bh * 2048 * 64;
  const int qw = tile * 128 + w * 32;
  const int q_abs = qw + ln31;
  const int nkv_w = qw / 64 + 1;
  const int nkv_b = tile * 2 + 2;
  const int swz = (ln31 & 7) << 4;

  bf16x8 qf[4];
#pragma unroll
  for (int dc = 0; dc < 4; ++dc)
    qf[dc] = *(const bf16x8*)(qh + bh_off + (size_t)(qw + ln31) * 64 + dc * 16 + hi * 8);

  const f32x16 Z16 = {0.f,0.f,0.f,0.f,0.f,0.f,0.f,0.f,0.f,0.f,0.f,0.f,0.f,0.f,0.f,0.f};
  f32x16 O0 = Z16, O1 = Z16;
  float m_run = -INFINITY, l_run = 0.f;

  uint4 kr0, kr1, vr0, vr1;
  const int srow = tid >> 2, sseg = tid & 3;
  const int sbase = srow * 128 + sseg * 32;
  const int sswz = (srow & 7) << 4;

  auto stage_load = [&](int kbi) {
    const unsigned short* kp = kh + bh_off + (size_t)(kbi * 64 + srow) * 64 + sseg * 16;
    kr0 = *(const uint4*)kp; kr1 = *(const uint4*)(kp + 8);
    const unsigned short* vp = vt + bh_off + (size_t)srow * 2048 + kbi * 64 + sseg * 16;
    vr0 = *(const uint4*)vp; vr1 = *(const uint4*)(vp + 8);
  };
  auto stage_write = [&](int bu) {
    *(uint4*)(Kb[bu] + (sbase ^ sswz)) = kr0;
    *(uint4*)(Kb[bu] + ((sbase + 16) ^ sswz)) = kr1;
    *(uint4*)(Vb[bu] + (sbase ^ sswz)) = vr0;
    *(uint4*)(Vb[bu] + ((sbase + 16) ^ sswz)) = vr1;
  };

  auto compute = [&](int kb, int cur) {
    const unsigned long long pmh = pmask[b * 32 + kb] >> (hi * 4);
    f32x16 S0 = Z16, S1 = Z16;
    __builtin_amdgcn_s_setprio(1);
#pragma unroll
    for (int dc = 0; dc < 4; ++dc) {
      bf16x8 k0 = *(const bf16x8*)(Kb[cur] + ((ln31 * 128 + dc * 32 + hi * 16) ^ swz));
      bf16x8 k1 = *(const bf16x8*)(Kb[cur] + (((ln31 + 32) * 128 + dc * 32 + hi * 16) ^ swz));
      S0 = __builtin_amdgcn_mfma_f32_32x32x16_bf16(k0, qf[dc], S0, 0, 0, 0);
      S1 = __builtin_amdgcn_mfma_f32_32x32x16_bf16(k1, qf[dc], S1, 0, 0, 0);
    }
    __builtin_amdgcn_s_setprio(0);

    const bool diag = (kb * 64 + 63) > qw;
    if (diag) {
#pragma unroll
      for (int r = 0; r < 16; ++r) {
        const int kloc = (r & 3) + 8 * (r >> 2);
        float sv = S0[r];
        sv = ((pmh >> kloc) & 1) ? NEG_BIG2
             : ((kb * 64 + kloc + 4 * hi > q_abs) ? sv + NEG_BIG2 : sv);
        S0[r] = sv;
        float sw = S1[r];
        sw = ((pmh >> (kloc + 32)) & 1) ? NEG_BIG2
             : ((kb * 64 + 32 + kloc + 4 * hi > q_abs) ? sw + NEG_BIG2 : sw);
        S1[r] = sw;
      }
    } else {
#pragma unroll
      for (int r = 0; r < 16; ++r) {
        const int kloc = (r & 3) + 8 * (r >> 2);
        S0[r] = ((pmh >> kloc) & 1) ? NEG_BIG2 : S0[r];
        S1[r] = ((pmh >> (kloc + 32)) & 1) ? NEG_BIG2 : S1[r];
      }
    }

    float vm = fmaxf(S0[0], S0[1]);
#pragma unroll
    for (int r = 2; r < 16; r += 2) vm = fmaxf(vm, fmaxf(S0[r], S0[r + 1]));
#pragma unroll
    for (int r = 0; r < 16; r += 2) vm = fmaxf(vm, fmaxf(S1[r], S1[r + 1]));
    vm = fmaxf(vm, __shfl_xor(vm, 32));

    if (__any(vm > m_run + 11.5f)) {
      const float mnew = fmaxf(m_run, vm);
      const float alpha = ex2(m_run - mnew);
      m_run = mnew;
      l_run *= alpha;
      O0 *= alpha; O1 *= alpha;
    }
    float rs = 0.f;
#pragma unroll
    for (int r = 0; r < 16; ++r) { float p = ex2(S0[r] - m_run); S0[r] = p; rs += p; }
#pragma unroll
    for (int r = 0; r < 16; ++r) { float p = ex2(S1[r] - m_run); S1[r] = p; rs += p; }
    rs += __shfl_xor(rs, 32);
    l_run += rs;

    union U8 { uint4 u; bf16x8 v; };
    bf16x8 pa[4];
#pragma unroll
    for (int kt = 0; kt < 2; ++kt) {
#pragma unroll
      for (int hf = 0; hf < 2; ++hf) {
        float p0, p1, p2, p3, p4, p5, p6, p7;
        if (kt == 0) {
          if (hf == 0) { p0=S0[0];p1=S0[1];p2=S0[2];p3=S0[3];p4=S0[4];p5=S0[5];p6=S0[6];p7=S0[7]; }
          else         { p0=S0[8];p1=S0[9];p2=S0[10];p3=S0[11];p4=S0[12];p5=S0[13];p6=S0[14];p7=S0[15]; }
        } else {
          if (hf == 0) { p0=S1[0];p1=S1[1];p2=S1[2];p3=S1[3];p4=S1[4];p5=S1[5];p6=S1[6];p7=S1[7]; }
          else         { p0=S1[8];p1=S1[9];p2=S1[10];p3=S1[11];p4=S1[12];p5=S1[13];p6=S1[14];p7=S1[15]; }
        }
        unsigned e0 = pk2(p0, p1), e1 = pk2(p2, p3);
        unsigned o0 = pk2(p4, p5), o1 = pk2(p6, p7);
        unsigned a0, b0_, a1, b1_;
        swap_pair(e0, o0, hi, a0, b0_);
        swap_pair(e1, o1, hi, a1, b1_);
        U8 u; u.u = make_uint4(a0, a1, b0_, b1_);
        pa[kt * 2 + hf] = u.v;
      }
    }

    __builtin_amdgcn_s_setprio(1);
#pragma unroll
    for (int c = 0; c < 4; ++c) {
      bf16x8 v0 = *(const bf16x8*)(Vb[cur] + ((ln31 * 128 + c * 32 + hi * 16) ^ swz));
      bf16x8 v1 = *(const bf16x8*)(Vb[cur] + (((ln31 + 32) * 128 + c * 32 + hi * 16) ^ swz));
      O0 = __builtin_amdgcn_mfma_f32_32x32x16_bf16(v0, pa[c], O0, 0, 0, 0);
      O1 = __builtin_amdgcn_mfma_f32_32x32x16_bf16(v1, pa[c], O1, 0, 0, 0);
    }
    __builtin_amdgcn_s_setprio(0);
  };

  // main causal loop: double-buffered, ONE barrier per step
  stage_load(0);
  stage_write(0);
  for (int kb = 0; kb < nkv_b; ++kb) {
    if (kb + 1 < nkv_b) stage_load(kb + 1);
    __syncthreads();
    if (kb < nkv_w) compute(kb, kb & 1);
    if (kb + 1 < nkv_b) stage_write((kb + 1) & 1);
  }

  // pathological rows (entire visible prefix padded): extend over all keys
  if (tid == 0) flagv = 0;
  __syncthreads();
  if (m_run <= -7.2e8f) flagv = 1;
  __syncthreads();
  if (flagv) {
    for (int kb = nkv_b - 1; kb < 32; ++kb) {
      if (kb + 1 < 32) stage_load(kb + 1);
      __syncthreads();
      if (kb >= nkv_w) compute(kb, kb & 1);
      if (kb + 1 < 32) stage_write((kb + 1) & 1);
    }
  }

  // epilogue: O0[r] = O[d=(r&3)+8*(r>>2)+4*hi][q=qw+ln31]; lane owns row q.
  {
    const float inv = 1.0f / l_run;
    unsigned short* op = ao + (size_t)(b * 2048 + qw + ln31) * 1024 + h * 64;
#pragma unroll
    for (int g2 = 0; g2 < 4; ++g2) {
      const int d0 = 8 * g2 + 4 * hi;
      *(ushort4*)(op + d0) = make_ushort4(
          f2b(O0[g2 * 4 + 0] * inv), f2b(O0[g2 * 4 + 1] * inv),
          f2b(O0[g2 * 4 + 2] * inv), f2b(O0[g2 * 4 + 3] * inv));
      *(ushort4*)(op + 32 + d0) = make_ushort4(
          f2b(O1[g2 * 4 + 0] * inv), f2b(O1[g2 * 4 + 1] * inv),
          f2b(O1[g2 * 4 + 2] * inv), f2b(O1[g2 * 4 + 3] * inv));
    }
  }
}

extern "C" void kernel_launch(void* const* d_in, const int* in_sizes, int n_in,
                              void* d_out, int out_size, void* d_ws, size_t ws_size,
                              hipStream_t stream) {
  const float* q  = (const float*)d_in[0];
  const float* k  = (const float*)d_in[1];
  const float* v  = (const float*)d_in[2];
  const void*  kpm = d_in[4];
  const float* Wq = (const float*)d_in[5];
  const float* Wk = (const float*)d_in[6];
  const float* Wv = (const float*)d_in[7];
  const float* Wo = (const float*)d_in[8];

  char* ws = (char*)d_ws;
  unsigned short* qh = (unsigned short*)(ws);                       // 8 MB (b,h,t,d)
  unsigned short* kh = (unsigned short*)(ws + (8u << 20));          // 8 MB
  unsigned short* vt = (unsigned short*)(ws + (16u << 20));         // 8 MB (b,h,d,t)
  unsigned short* ao = (unsigned short*)(ws + (24u << 20));         // 8 MB (B*T, D)
  unsigned short* Wb = (unsigned short*)(ws + (32u << 20));         // 8 MB (4 x 1M)
  float* sin_t = (float*)(ws + (40u << 20));                        // 512 KB
  float* cos_t = (float*)(ws + (40u << 20) + 524288);               // 512 KB
  unsigned long long* pmask = (unsigned long long*)(ws + (41u << 20));  // 512 B
  unsigned short* qb = (unsigned short*)(ws + (42u << 20));         // 8 MB bf16 q
  unsigned short* kb = (unsigned short*)(ws + (50u << 20));         // 8 MB bf16 k
  unsigned short* vb = (unsigned short*)(ws + (58u << 20));         // 8 MB bf16 v

  const bool big = ws_size >= (66ull << 20);

  prep_k<<<big ? 8705 : 2561, 256, 0, stream>>>(
      kpm, Wq, Wk, Wv, Wo, q, k, v, pmask, sin_t, cos_t, Wb, qb, kb, vb);

  dim3 gq(32, 8, 3);
  if (big) {
    qkv_k<true><<<gq, 256, 0, stream>>>(qb, kb, vb, Wb, sin_t, cos_t, qh, kh, vt);
  } else {
    qkv_k<false><<<gq, 256, 0, stream>>>(q, k, v, Wb, sin_t, cos_t, qh, kh, vt);
  }

  attn_k<<<512, 256, 0, stream>>>(qh, kh, vt, pmask, ao);

  gemm_o_k<<<dim3(64, 8), 256, 0, stream>>>(ao, Wb + 3145728, (float*)d_out);
}